// Round 2
// baseline (1183.704 us; speedup 1.0000x reference)
//
#include <hip/hip_runtime.h>

__device__ __forceinline__ float leaky(float v) { return v >= 0.f ? v : 0.01f * v; }

__device__ __forceinline__ void fma4(float4& a, float s, const float4& w) {
    a.x = fmaf(s, w.x, a.x); a.y = fmaf(s, w.y, a.y);
    a.z = fmaf(s, w.z, a.z); a.w = fmaf(s, w.w, a.w);
}

// ---------------------------------------------------------------------------
// CSR build (unchanged)
__global__ void k_deg(const int* __restrict__ col, int E, int* __restrict__ deg) {
    int e = blockIdx.x * blockDim.x + threadIdx.x;
    if (e < E) atomicAdd(&deg[col[e]], 1);
}

__global__ __launch_bounds__(256) void k_scan_part(const int* __restrict__ deg,
                                                   int* __restrict__ part,
                                                   int* __restrict__ bsum, int N) {
    __shared__ int tmp[256];
    int tid = threadIdx.x;
    int i = blockIdx.x * 256 + tid;
    int v = (i < N) ? deg[i] : 0;
    tmp[tid] = v;
    __syncthreads();
    for (int ofs = 1; ofs < 256; ofs <<= 1) {
        int t = (tid >= ofs) ? tmp[tid - ofs] : 0;
        __syncthreads();
        tmp[tid] += t;
        __syncthreads();
    }
    int incl = tmp[tid];
    if (i < N) part[i] = incl - v;
    if (tid == 255) bsum[blockIdx.x] = incl;
}

__global__ __launch_bounds__(256) void k_scan_sums(const int* __restrict__ bsum,
                                                   int* __restrict__ boff, int NB,
                                                   int* __restrict__ offs_last) {
    __shared__ int tmp[256];
    int tid = threadIdx.x;
    int v = (tid < NB) ? bsum[tid] : 0;
    tmp[tid] = v;
    __syncthreads();
    for (int ofs = 1; ofs < 256; ofs <<= 1) {
        int t = (tid >= ofs) ? tmp[tid - ofs] : 0;
        __syncthreads();
        tmp[tid] += t;
        __syncthreads();
    }
    int incl = tmp[tid];
    if (tid < NB) boff[tid] = incl - v;
    if (tid == 255) offs_last[0] = incl;
}

__global__ __launch_bounds__(256) void k_scan_final(const int* __restrict__ part,
                                                    const int* __restrict__ boff,
                                                    const int* __restrict__ deg,
                                                    int* __restrict__ offs,
                                                    int* __restrict__ pos,
                                                    float* __restrict__ dinv, int N) {
    int i = blockIdx.x * 256 + threadIdx.x;
    if (i < N) {
        int o = part[i] + boff[blockIdx.x];
        offs[i] = o;
        pos[i] = o;
        dinv[i] = rsqrtf((float)(deg[i] + 1));
    }
}

__global__ void k_fill(const int* __restrict__ row, const int* __restrict__ col, int E,
                       int* __restrict__ pos, int* __restrict__ csr) {
    int e = blockIdx.x * blockDim.x + threadIdx.x;
    if (e < E) {
        int p = atomicAdd(&pos[col[e]], 1);
        csr[p] = row[e];
    }
}

// ---------------------------------------------------------------------------
// Phase A: x1[:, f*16 .. f*16+15] = leaky(X_f @ W_f + b_f), X_f [N,768], W [768,16]
// 128-node tile, 24 chunks of 32 k. Register blocking: thread = (nq, jq, kq):
// 8 nodes x 4 j x 8 k-per-chunk. acc reduced across the 4 kq waves via LDS.
// LDS: xs double-buffered swizzled [128][8] float4 + ws [32][4] float4.
__global__ __launch_bounds__(256, 4) void k_featB(
    const float* __restrict__ s, const float* __restrict__ d, const float* __restrict__ t,
    const float* __restrict__ Ws, const float* __restrict__ bs2,
    const float* __restrict__ Wd, const float* __restrict__ bd2,
    const float* __restrict__ Wt, const float* __restrict__ bt2,
    float* __restrict__ x1g, int N, int NG) {
    __shared__ float4 smem[2304];  // [2][1024] xs + [2][128] ws = 36 KB

    const int bid = blockIdx.x;
    const int f = bid / NG;
    const int grp = bid - f * NG;
    const float* __restrict__ X = (f == 0) ? s : ((f == 1) ? d : t);
    const float* __restrict__ W = (f == 0) ? Ws : ((f == 1) ? Wd : Wt);
    const float* __restrict__ B = (f == 0) ? bs2 : ((f == 1) ? bd2 : bt2);
    const int n0 = grp * 128;
    const int tid = threadIdx.x;
    const int lane = tid & 63;
    const int kq = tid >> 6;       // wave id = k-quarter
    const int nq = lane & 15;
    const int jq = lane >> 4;      // 0..3

    float4 rx[4];
    float4 rw;

    auto load_g = [&](int c) {
#pragma unroll
        for (int v = 0; v < 4; ++v) {
            int L = v * 256 + tid;
            int n = L >> 3, c4 = L & 7;
            int nn = n0 + n; if (nn >= N) nn = N - 1;
            rx[v] = *reinterpret_cast<const float4*>(X + (size_t)nn * 768 + c * 32 + c4 * 4);
        }
        if (tid < 128)
            rw = *reinterpret_cast<const float4*>(W + (size_t)(c * 128 + tid) * 4);
    };
    auto write_l = [&](int b) {
        float4* xs4 = smem + b * 1024;
        float4* ws4 = smem + 2048 + b * 128;
#pragma unroll
        for (int v = 0; v < 4; ++v) {
            int L = v * 256 + tid;
            int n = L >> 3, c4 = L & 7;
            xs4[n * 8 + (c4 ^ (n & 7))] = rx[v];
        }
        if (tid < 128) ws4[tid] = rw;
    };

    float4 acc[8];
#pragma unroll
    for (int g = 0; g < 8; ++g) acc[g] = make_float4(0.f, 0.f, 0.f, 0.f);

    // prologue
    load_g(0);
    write_l(0);
    load_g(1);
    __syncthreads();

    for (int c = 0; c < 24; ++c) {
        const int b = c & 1;
        const float4* xs4 = smem + b * 1024;
        const float4* ws4 = smem + 2048 + b * 128;
#pragma unroll
        for (int step = 0; step < 2; ++step) {
            int k = kq * 8 + step * 4;
            float4 w0 = ws4[(k + 0) * 4 + jq];
            float4 w1 = ws4[(k + 1) * 4 + jq];
            float4 w2 = ws4[(k + 2) * 4 + jq];
            float4 w3 = ws4[(k + 3) * 4 + jq];
            int k4 = k >> 2;
#pragma unroll
            for (int g = 0; g < 8; ++g) {
                int n = nq + (g << 4);
                float4 xv = xs4[n * 8 + (k4 ^ (n & 7))];
                fma4(acc[g], xv.x, w0);
                fma4(acc[g], xv.y, w1);
                fma4(acc[g], xv.z, w2);
                fma4(acc[g], xv.w, w3);
            }
        }
        if (c < 23) {
            write_l((c + 1) & 1);
            if (c < 22) load_g(c + 2);
        }
        __syncthreads();
    }

    // cross-wave (kq) reduction via LDS: red[lane][g][kq], stride 33 to spread banks
    float4* red4 = smem;
#pragma unroll
    for (int g = 0; g < 8; ++g)
        red4[lane * 33 + g * 4 + kq] = acc[g];
    __syncthreads();

    float4 bq[4];
#pragma unroll
    for (int j4 = 0; j4 < 4; ++j4) bq[j4] = *reinterpret_cast<const float4*>(B + j4 * 4);

#pragma unroll
    for (int half = 0; half < 2; ++half) {
        int idx = half * 256 + tid;       // 0..511 = (lane_r, g_r)
        int lane_r = idx & 63;
        int g_r = idx >> 6;
        float4 a0 = red4[lane_r * 33 + g_r * 4 + 0];
        float4 a1 = red4[lane_r * 33 + g_r * 4 + 1];
        float4 a2 = red4[lane_r * 33 + g_r * 4 + 2];
        float4 a3 = red4[lane_r * 33 + g_r * 4 + 3];
        int j4 = lane_r >> 4;
        float4 bb = bq[j4];
        float4 r;
        r.x = leaky(a0.x + a1.x + a2.x + a3.x + bb.x);
        r.y = leaky(a0.y + a1.y + a2.y + a3.y + bb.y);
        r.z = leaky(a0.z + a1.z + a2.z + a3.z + bb.z);
        r.w = leaky(a0.w + a1.w + a2.w + a3.w + bb.w);
        int n = (lane_r & 15) + (g_r << 4);
        if (n0 + n < N)
            *reinterpret_cast<float4*>(x1g + (size_t)(n0 + n) * 64 + f * 16 + j4 * 4) = r;
    }
}

// ---------------------------------------------------------------------------
// Tiny linears: x1[:, 48..63] from profile (5->8) and personal (7->8)
__global__ __launch_bounds__(256) void k_small(const float* __restrict__ prof,
                                               const float* __restrict__ pers,
                                               const float* __restrict__ Wp, const float* __restrict__ bp,
                                               const float* __restrict__ Wpe, const float* __restrict__ bpe,
                                               float* __restrict__ x1g, int N) {
    int n = blockIdx.x * blockDim.x + threadIdx.x;
    if (n >= N) return;
    float pv[5], pe[7];
#pragma unroll
    for (int i = 0; i < 5; ++i) pv[i] = prof[(size_t)n * 5 + i];
#pragma unroll
    for (int i = 0; i < 7; ++i) pe[i] = pers[(size_t)n * 7 + i];
    float o[16];
#pragma unroll
    for (int j = 0; j < 8; ++j) {
        float a = bp[j];
#pragma unroll
        for (int i = 0; i < 5; ++i) a = fmaf(pv[i], Wp[i * 8 + j], a);
        o[j] = leaky(a);
        float a2 = bpe[j];
#pragma unroll
        for (int i = 0; i < 7; ++i) a2 = fmaf(pe[i], Wpe[i * 8 + j], a2);
        o[8 + j] = leaky(a2);
    }
#pragma unroll
    for (int v = 0; v < 4; ++v)
        *reinterpret_cast<float4*>(x1g + (size_t)n * 64 + 48 + v * 4) =
            make_float4(o[v * 4], o[v * 4 + 1], o[v * 4 + 2], o[v * 4 + 3]);
}

// ---------------------------------------------------------------------------
// Generic 64x64 node-matmul: out = act( xin @ W [+ bias] ) [* dinv]
// thread = (nq 0..15, jq 0..15): 4 nodes x 4 j, full k. float4 LDS reads.
__global__ __launch_bounds__(256, 4) void k_mm64(const float* __restrict__ xin,
                                                 const float* __restrict__ W,
                                                 const float* __restrict__ bias,
                                                 const float* __restrict__ dinvv,
                                                 int act,
                                                 float* __restrict__ out, int N) {
    __shared__ float4 xt4[1024];  // [64][16] swizzled
    __shared__ float4 wt4[1024];  // [64 k][16 j4] linear
    const int tid = threadIdx.x;
    const int n0 = blockIdx.x * 64;
#pragma unroll
    for (int v = 0; v < 4; ++v) {
        int L = v * 256 + tid;
        int n = L >> 4, c4 = L & 15;
        int nn = n0 + n; if (nn >= N) nn = N - 1;
        xt4[n * 16 + (c4 ^ (n & 15))] = *reinterpret_cast<const float4*>(xin + (size_t)nn * 64 + c4 * 4);
        wt4[L] = *reinterpret_cast<const float4*>(W + (size_t)L * 4);
    }
    __syncthreads();
    const int nq = tid & 15;
    const int jq = tid >> 4;  // 0..15
    float4 acc[4];
#pragma unroll
    for (int g = 0; g < 4; ++g) acc[g] = make_float4(0.f, 0.f, 0.f, 0.f);
    for (int k = 0; k < 64; k += 4) {
        float4 w0 = wt4[(k + 0) * 16 + jq];
        float4 w1 = wt4[(k + 1) * 16 + jq];
        float4 w2 = wt4[(k + 2) * 16 + jq];
        float4 w3 = wt4[(k + 3) * 16 + jq];
        int k4 = k >> 2;
#pragma unroll
        for (int g = 0; g < 4; ++g) {
            int n = nq + (g << 4);
            float4 xv = xt4[n * 16 + (k4 ^ (n & 15))];
            fma4(acc[g], xv.x, w0);
            fma4(acc[g], xv.y, w1);
            fma4(acc[g], xv.z, w2);
            fma4(acc[g], xv.w, w3);
        }
    }
    float4 bb = make_float4(0.f, 0.f, 0.f, 0.f);
    if (bias) bb = *reinterpret_cast<const float4*>(bias + jq * 4);
#pragma unroll
    for (int g = 0; g < 4; ++g) {
        int n = nq + (g << 4);
        if (n0 + n >= N) continue;
        float4 r = acc[g];
        r.x += bb.x; r.y += bb.y; r.z += bb.z; r.w += bb.w;
        if (act) { r.x = leaky(r.x); r.y = leaky(r.y); r.z = leaky(r.z); r.w = leaky(r.w); }
        if (dinvv) {
            float dv = dinvv[n0 + n];
            r.x *= dv; r.y *= dv; r.z *= dv; r.w *= dv;
        }
        *reinterpret_cast<float4*>(out + (size_t)(n0 + n) * 64 + jq * 4) = r;
    }
}

// ---------------------------------------------------------------------------
// Gather aggregation (unchanged): one wave per node, lane = feature dim
__global__ __launch_bounds__(256) void k_agg(const float* __restrict__ z,
                                             const int* __restrict__ offs,
                                             const int* __restrict__ csr,
                                             const float* __restrict__ dinv,
                                             const float* __restrict__ bias,
                                             const float* __restrict__ x1,
                                             float* __restrict__ xout, int N) {
    int lane = threadIdx.x & 63;
    int c = blockIdx.x * 4 + (threadIdx.x >> 6);
    if (c >= N) return;
    float acc = z[(size_t)c * 64 + lane];
    int s = offs[c], e = offs[c + 1];
    for (int j0 = s; j0 < e; j0 += 64) {
        int cnt = e - j0;
        if (cnt > 64) cnt = 64;
        int idx = (j0 + lane < e) ? csr[j0 + lane] : 0;
        for (int d = 0; d < cnt; ++d) {
            int r = __shfl(idx, d, 64);
            acc += z[(size_t)r * 64 + lane];
        }
    }
    xout[(size_t)c * 64 + lane] = dinv[c] * acc + bias[lane] + x1[(size_t)c * 64 + lane];
}

// ---------------------------------------------------------------------------
// head (unchanged)
__global__ __launch_bounds__(256) void k_head(const float* __restrict__ xin,
                                              const float* __restrict__ Wo1,
                                              const float* __restrict__ bo1,
                                              const float* __restrict__ Wo2,
                                              const float* __restrict__ bo2,
                                              float* __restrict__ out, int N) {
    __shared__ float xsg[64][65];
    __shared__ float wg[64][65];
    __shared__ float hs[64][65];
    __shared__ float wo2[128];
    const int tid = threadIdx.x;
    const int n0 = blockIdx.x * 64;
#pragma unroll
    for (int v = 0; v < 4; ++v) {
        int idx = tid + v * 256;
        int n = idx >> 4;
        int jj = (idx & 15) << 2;
        float4 xv = make_float4(0.f, 0.f, 0.f, 0.f);
        if (n0 + n < N) xv = *reinterpret_cast<const float4*>(xin + (size_t)(n0 + n) * 64 + jj);
        xsg[n][jj] = xv.x; xsg[n][jj + 1] = xv.y; xsg[n][jj + 2] = xv.z; xsg[n][jj + 3] = xv.w;
        float4 w = *reinterpret_cast<const float4*>(Wo1 + (size_t)n * 64 + jj);
        wg[n][jj] = w.x; wg[n][jj + 1] = w.y; wg[n][jj + 2] = w.z; wg[n][jj + 3] = w.w;
    }
    if (tid < 128) wo2[tid] = Wo2[tid];
    __syncthreads();
    int j = tid & 63;
    int g = tid >> 6;
    float bj = bo1[j];
    for (int i = 0; i < 16; ++i) {
        int n = g * 16 + i;
        float a = bj;
#pragma unroll
        for (int k = 0; k < 64; ++k) a += xsg[n][k] * wg[k][j];
        hs[n][j] = leaky(a);
    }
    __syncthreads();
    if (tid < 128) {
        int n = tid >> 1;
        int j2 = tid & 1;
        float a = bo2[j2];
#pragma unroll
        for (int k = 0; k < 64; ++k) a += hs[n][k] * wo2[k * 2 + j2];
        if (n0 + n < N) out[(size_t)(n0 + n) * 2 + j2] = 1.f / (1.f + expf(-a));
    }
}

// ---------------------------------------------------------------------------
extern "C" void kernel_launch(void* const* d_in, const int* in_sizes, int n_in,
                              void* d_out, int out_size, void* d_ws, size_t ws_size,
                              hipStream_t stream) {
    const float* screen   = (const float*)d_in[0];
    const float* des      = (const float*)d_in[1];
    const float* tweet    = (const float*)d_in[2];
    const float* profile  = (const float*)d_in[3];
    const float* personal = (const float*)d_in[4];
    const int*   edge     = (const int*)d_in[5];
    const float* Ws  = (const float*)d_in[6],  *bs  = (const float*)d_in[7];
    const float* Wd  = (const float*)d_in[8],  *bd  = (const float*)d_in[9];
    const float* Wt  = (const float*)d_in[10], *bt  = (const float*)d_in[11];
    const float* Wp  = (const float*)d_in[12], *bp  = (const float*)d_in[13];
    const float* Wpe = (const float*)d_in[14], *bpe = (const float*)d_in[15];
    const float* Wl  = (const float*)d_in[16], *bl  = (const float*)d_in[17];
    const float* Wg1 = (const float*)d_in[18], *bg1 = (const float*)d_in[19];
    const float* Wg2 = (const float*)d_in[20], *bg2 = (const float*)d_in[21];
    const float* Wg3 = (const float*)d_in[22], *bg3 = (const float*)d_in[23];
    const float* Wo1 = (const float*)d_in[24], *bo1 = (const float*)d_in[25];
    const float* Wo2 = (const float*)d_in[26], *bo2 = (const float*)d_in[27];

    const int N = in_sizes[0] / 768;   // 50000
    const int E = in_sizes[5] / 2;     // 1600000
    const int* row = edge;
    const int* col = edge + E;

    size_t off = 0;
    auto alloc = [&](size_t bytes) -> void* {
        void* p = (char*)d_ws + off;
        off += (bytes + 255) & ~(size_t)255;
        return p;
    };
    const size_t NF = (size_t)N * 64;
    float* x1   = (float*)alloc(NF * 4);
    float* xa   = (float*)alloc(NF * 4);
    float* xb   = (float*)alloc(NF * 4);
    float* z    = (float*)alloc(NF * 4);
    float* dinv = (float*)alloc((size_t)N * 4);
    int* deg  = (int*)alloc((size_t)N * 4);
    int* part = (int*)alloc((size_t)N * 4);
    int* offs = (int*)alloc((size_t)(N + 1) * 4);
    int* pos  = (int*)alloc((size_t)N * 4);
    int* csr  = (int*)alloc((size_t)E * 4);
    const int NB = (N + 255) / 256;
    int* bsum = (int*)alloc((size_t)NB * 4);
    int* boff = (int*)alloc((size_t)NB * 4);
    (void)ws_size; (void)n_in; (void)out_size;

    // CSR build
    hipMemsetAsync(deg, 0, (size_t)N * 4, stream);
    k_deg<<<(E + 255) / 256, 256, 0, stream>>>(col, E, deg);
    k_scan_part<<<NB, 256, 0, stream>>>(deg, part, bsum, N);
    k_scan_sums<<<1, 256, 0, stream>>>(bsum, boff, NB, offs + N);
    k_scan_final<<<NB, 256, 0, stream>>>(part, boff, deg, offs, pos, dinv, N);
    k_fill<<<(E + 255) / 256, 256, 0, stream>>>(row, col, E, pos, csr);

    // Phase A: big feature linears (128-node tiles, 3 features in one grid)
    const int NG2 = (N + 127) / 128;
    k_featB<<<NG2 * 3, 256, 0, stream>>>(screen, des, tweet, Ws, bs, Wd, bd, Wt, bt, x1, N, NG2);
    k_small<<<(N + 255) / 256, 256, 0, stream>>>(profile, personal, Wp, bp, Wpe, bpe, x1, N);

    const int NGB = (N + 63) / 64;
    // x = leaky(x1 @ Wl + bl)
    k_mm64<<<NGB, 256, 0, stream>>>(x1, Wl, bl, nullptr, 1, xa, N);

    const int NAB = (N + 3) / 4;
    // layer 1
    k_mm64<<<NGB, 256, 0, stream>>>(xa, Wg1, nullptr, dinv, 0, z, N);
    k_agg<<<NAB, 256, 0, stream>>>(z, offs, csr, dinv, bg1, x1, xb, N);
    // layer 2
    k_mm64<<<NGB, 256, 0, stream>>>(xb, Wg2, nullptr, dinv, 0, z, N);
    k_agg<<<NAB, 256, 0, stream>>>(z, offs, csr, dinv, bg2, x1, xa, N);
    // layer 3
    k_mm64<<<NGB, 256, 0, stream>>>(xa, Wg3, nullptr, dinv, 0, z, N);
    k_agg<<<NAB, 256, 0, stream>>>(z, offs, csr, dinv, bg3, x1, xb, N);

    // head
    k_head<<<NGB, 256, 0, stream>>>(xb, Wo1, bo1, Wo2, bo2, (float*)d_out, N);
}

// Round 3
// 690.797 us; speedup vs baseline: 1.7135x; 1.7135x over previous
//
#include <hip/hip_runtime.h>

__device__ __forceinline__ float leaky(float v) { return v >= 0.f ? v : 0.01f * v; }

__device__ __forceinline__ void fma4(float4& a, float s, const float4& w) {
    a.x = fmaf(s, w.x, a.x); a.y = fmaf(s, w.y, a.y);
    a.z = fmaf(s, w.z, a.z); a.w = fmaf(s, w.w, a.w);
}

#define GLOAD_LDS16(gp, lp) \
    __builtin_amdgcn_global_load_lds( \
        (const __attribute__((address_space(1))) void*)(gp), \
        (__attribute__((address_space(3))) void*)(lp), 16, 0, 0)

// ---------------------------------------------------------------------------
// CSR build (unchanged)
__global__ void k_deg(const int* __restrict__ col, int E, int* __restrict__ deg) {
    int e = blockIdx.x * blockDim.x + threadIdx.x;
    if (e < E) atomicAdd(&deg[col[e]], 1);
}

__global__ __launch_bounds__(256) void k_scan_part(const int* __restrict__ deg,
                                                   int* __restrict__ part,
                                                   int* __restrict__ bsum, int N) {
    __shared__ int tmp[256];
    int tid = threadIdx.x;
    int i = blockIdx.x * 256 + tid;
    int v = (i < N) ? deg[i] : 0;
    tmp[tid] = v;
    __syncthreads();
    for (int ofs = 1; ofs < 256; ofs <<= 1) {
        int t = (tid >= ofs) ? tmp[tid - ofs] : 0;
        __syncthreads();
        tmp[tid] += t;
        __syncthreads();
    }
    int incl = tmp[tid];
    if (i < N) part[i] = incl - v;
    if (tid == 255) bsum[blockIdx.x] = incl;
}

__global__ __launch_bounds__(256) void k_scan_sums(const int* __restrict__ bsum,
                                                   int* __restrict__ boff, int NB,
                                                   int* __restrict__ offs_last) {
    __shared__ int tmp[256];
    int tid = threadIdx.x;
    int v = (tid < NB) ? bsum[tid] : 0;
    tmp[tid] = v;
    __syncthreads();
    for (int ofs = 1; ofs < 256; ofs <<= 1) {
        int t = (tid >= ofs) ? tmp[tid - ofs] : 0;
        __syncthreads();
        tmp[tid] += t;
        __syncthreads();
    }
    int incl = tmp[tid];
    if (tid < NB) boff[tid] = incl - v;
    if (tid == 255) offs_last[0] = incl;
}

__global__ __launch_bounds__(256) void k_scan_final(const int* __restrict__ part,
                                                    const int* __restrict__ boff,
                                                    const int* __restrict__ deg,
                                                    int* __restrict__ offs,
                                                    int* __restrict__ pos,
                                                    float* __restrict__ dinv, int N) {
    int i = blockIdx.x * 256 + threadIdx.x;
    if (i < N) {
        int o = part[i] + boff[blockIdx.x];
        offs[i] = o;
        pos[i] = o;
        dinv[i] = rsqrtf((float)(deg[i] + 1));
    }
}

__global__ void k_fill(const int* __restrict__ row, const int* __restrict__ col, int E,
                       int* __restrict__ pos, int* __restrict__ csr) {
    int e = blockIdx.x * blockDim.x + threadIdx.x;
    if (e < E) {
        int p = atomicAdd(&pos[col[e]], 1);
        csr[p] = row[e];
    }
}

// ---------------------------------------------------------------------------
// Phase A: x1[:, f*16 .. f*16+15] = leaky(X_f @ W_f + b_f), X_f [N,768], W [768,16]
// 128-node tile, 24 chunks of 32 k. Staging via global_load_lds (no VGPR
// round-trip, no spill): linear LDS dest + pre-swizzled global source, read
// side applies the same XOR. One __syncthreads per chunk (m97 pattern).
__global__ __attribute__((amdgpu_waves_per_eu(4, 4))) __launch_bounds__(256)
void k_featB(
    const float* __restrict__ s, const float* __restrict__ d, const float* __restrict__ t,
    const float* __restrict__ Ws, const float* __restrict__ bs2,
    const float* __restrict__ Wd, const float* __restrict__ bd2,
    const float* __restrict__ Wt, const float* __restrict__ bt2,
    float* __restrict__ x1g, int N, int NG) {
    __shared__ float4 smem[2304];  // [2][1024] xs + [2][128] ws = 36 KB

    const int bid = blockIdx.x;
    const int f = bid / NG;
    const int grp = bid - f * NG;
    const float* __restrict__ X = (f == 0) ? s : ((f == 1) ? d : t);
    const float* __restrict__ W = (f == 0) ? Ws : ((f == 1) ? Wd : Wt);
    const float* __restrict__ B = (f == 0) ? bs2 : ((f == 1) ? bd2 : bt2);
    const int n0 = grp * 128;
    const int tid = threadIdx.x;
    const int lane = tid & 63;
    const int wid = tid >> 6;      // wave id = k-quarter for compute
    const int kq = wid;
    const int nq = lane & 15;
    const int jq = lane >> 4;      // 0..3

    // stage chunk c into buffer b (issue only; completion at next barrier)
    auto stage = [&](int c, int b) {
        float4* xs4 = smem + b * 1024;
        float4* ws4 = smem + 2048 + b * 128;
#pragma unroll
        for (int v = 0; v < 4; ++v) {
            int L = wid * 256 + v * 64 + lane;   // linear LDS float4 slot
            int n = L >> 3, ss = L & 7;
            int c4 = ss ^ (n & 7);               // inverse-swizzled source col
            int nn = n0 + n; if (nn >= N) nn = N - 1;
            const float* g = X + (size_t)nn * 768 + c * 32 + c4 * 4;
            GLOAD_LDS16(g, xs4 + wid * 256 + v * 64);
        }
        if (wid < 2) {
            const float* g = W + (size_t)c * 512 + ((wid & 1) * 64 + lane) * 4;
            GLOAD_LDS16(g, ws4 + (wid & 1) * 64);
        }
    };

    float4 acc[8];
#pragma unroll
    for (int g = 0; g < 8; ++g) acc[g] = make_float4(0.f, 0.f, 0.f, 0.f);

    stage(0, 0);
    __syncthreads();  // drains vmcnt -> chunk 0 resident

    for (int c = 0; c < 24; ++c) {
        const int b = c & 1;
        if (c < 23) stage(c + 1, b ^ 1);  // issue next-chunk loads first
        const float4* xs4 = smem + b * 1024;
        const float4* ws4 = smem + 2048 + b * 128;
#pragma unroll
        for (int step = 0; step < 2; ++step) {
            int k = kq * 8 + step * 4;
            float4 w0 = ws4[(k + 0) * 4 + jq];
            float4 w1 = ws4[(k + 1) * 4 + jq];
            float4 w2 = ws4[(k + 2) * 4 + jq];
            float4 w3 = ws4[(k + 3) * 4 + jq];
            int k4 = k >> 2;
#pragma unroll
            for (int g = 0; g < 8; ++g) {
                int n = nq + (g << 4);
                float4 xv = xs4[n * 8 + (k4 ^ (n & 7))];
                fma4(acc[g], xv.x, w0);
                fma4(acc[g], xv.y, w1);
                fma4(acc[g], xv.z, w2);
                fma4(acc[g], xv.w, w3);
            }
        }
        __syncthreads();  // drain next-chunk loads + guard buffer reuse
    }

    // cross-wave (kq) reduction via LDS: red[lane][g][kq], stride 33
    float4* red4 = smem;
#pragma unroll
    for (int g = 0; g < 8; ++g)
        red4[lane * 33 + g * 4 + kq] = acc[g];
    __syncthreads();

    float4 bq[4];
#pragma unroll
    for (int j4 = 0; j4 < 4; ++j4) bq[j4] = *reinterpret_cast<const float4*>(B + j4 * 4);

#pragma unroll
    for (int half = 0; half < 2; ++half) {
        int idx = half * 256 + tid;       // 0..511 = (lane_r, g_r)
        int lane_r = idx & 63;
        int g_r = idx >> 6;
        float4 a0 = red4[lane_r * 33 + g_r * 4 + 0];
        float4 a1 = red4[lane_r * 33 + g_r * 4 + 1];
        float4 a2 = red4[lane_r * 33 + g_r * 4 + 2];
        float4 a3 = red4[lane_r * 33 + g_r * 4 + 3];
        int j4 = lane_r >> 4;
        float4 bb = bq[j4];
        float4 r;
        r.x = leaky(a0.x + a1.x + a2.x + a3.x + bb.x);
        r.y = leaky(a0.y + a1.y + a2.y + a3.y + bb.y);
        r.z = leaky(a0.z + a1.z + a2.z + a3.z + bb.z);
        r.w = leaky(a0.w + a1.w + a2.w + a3.w + bb.w);
        int n = (lane_r & 15) + (g_r << 4);
        if (n0 + n < N)
            *reinterpret_cast<float4*>(x1g + (size_t)(n0 + n) * 64 + f * 16 + j4 * 4) = r;
    }
}

// ---------------------------------------------------------------------------
// Tiny linears: x1[:, 48..63] from profile (5->8) and personal (7->8)
__global__ __launch_bounds__(256) void k_small(const float* __restrict__ prof,
                                               const float* __restrict__ pers,
                                               const float* __restrict__ Wp, const float* __restrict__ bp,
                                               const float* __restrict__ Wpe, const float* __restrict__ bpe,
                                               float* __restrict__ x1g, int N) {
    int n = blockIdx.x * blockDim.x + threadIdx.x;
    if (n >= N) return;
    float pv[5], pe[7];
#pragma unroll
    for (int i = 0; i < 5; ++i) pv[i] = prof[(size_t)n * 5 + i];
#pragma unroll
    for (int i = 0; i < 7; ++i) pe[i] = pers[(size_t)n * 7 + i];
    float o[16];
#pragma unroll
    for (int j = 0; j < 8; ++j) {
        float a = bp[j];
#pragma unroll
        for (int i = 0; i < 5; ++i) a = fmaf(pv[i], Wp[i * 8 + j], a);
        o[j] = leaky(a);
        float a2 = bpe[j];
#pragma unroll
        for (int i = 0; i < 7; ++i) a2 = fmaf(pe[i], Wpe[i * 8 + j], a2);
        o[8 + j] = leaky(a2);
    }
#pragma unroll
    for (int v = 0; v < 4; ++v)
        *reinterpret_cast<float4*>(x1g + (size_t)n * 64 + 48 + v * 4) =
            make_float4(o[v * 4], o[v * 4 + 1], o[v * 4 + 2], o[v * 4 + 3]);
}

// ---------------------------------------------------------------------------
// Generic 64x64 node-matmul: out = act( xin @ W [+ bias] ) [* dinv]
__global__ __launch_bounds__(256, 4) void k_mm64(const float* __restrict__ xin,
                                                 const float* __restrict__ W,
                                                 const float* __restrict__ bias,
                                                 const float* __restrict__ dinvv,
                                                 int act,
                                                 float* __restrict__ out, int N) {
    __shared__ float4 xt4[1024];  // [64][16] swizzled
    __shared__ float4 wt4[1024];  // [64 k][16 j4] linear
    const int tid = threadIdx.x;
    const int n0 = blockIdx.x * 64;
#pragma unroll
    for (int v = 0; v < 4; ++v) {
        int L = v * 256 + tid;
        int n = L >> 4, c4 = L & 15;
        int nn = n0 + n; if (nn >= N) nn = N - 1;
        xt4[n * 16 + (c4 ^ (n & 15))] = *reinterpret_cast<const float4*>(xin + (size_t)nn * 64 + c4 * 4);
        wt4[L] = *reinterpret_cast<const float4*>(W + (size_t)L * 4);
    }
    __syncthreads();
    const int nq = tid & 15;
    const int jq = tid >> 4;  // 0..15
    float4 acc[4];
#pragma unroll
    for (int g = 0; g < 4; ++g) acc[g] = make_float4(0.f, 0.f, 0.f, 0.f);
    for (int k = 0; k < 64; k += 4) {
        float4 w0 = wt4[(k + 0) * 16 + jq];
        float4 w1 = wt4[(k + 1) * 16 + jq];
        float4 w2 = wt4[(k + 2) * 16 + jq];
        float4 w3 = wt4[(k + 3) * 16 + jq];
        int k4 = k >> 2;
#pragma unroll
        for (int g = 0; g < 4; ++g) {
            int n = nq + (g << 4);
            float4 xv = xt4[n * 16 + (k4 ^ (n & 15))];
            fma4(acc[g], xv.x, w0);
            fma4(acc[g], xv.y, w1);
            fma4(acc[g], xv.z, w2);
            fma4(acc[g], xv.w, w3);
        }
    }
    float4 bb = make_float4(0.f, 0.f, 0.f, 0.f);
    if (bias) bb = *reinterpret_cast<const float4*>(bias + jq * 4);
#pragma unroll
    for (int g = 0; g < 4; ++g) {
        int n = nq + (g << 4);
        if (n0 + n >= N) continue;
        float4 r = acc[g];
        r.x += bb.x; r.y += bb.y; r.z += bb.z; r.w += bb.w;
        if (act) { r.x = leaky(r.x); r.y = leaky(r.y); r.z = leaky(r.z); r.w = leaky(r.w); }
        if (dinvv) {
            float dv = dinvv[n0 + n];
            r.x *= dv; r.y *= dv; r.z *= dv; r.w *= dv;
        }
        *reinterpret_cast<float4*>(out + (size_t)(n0 + n) * 64 + jq * 4) = r;
    }
}

// ---------------------------------------------------------------------------
// Gather aggregation (unchanged): one wave per node, lane = feature dim
__global__ __launch_bounds__(256) void k_agg(const float* __restrict__ z,
                                             const int* __restrict__ offs,
                                             const int* __restrict__ csr,
                                             const float* __restrict__ dinv,
                                             const float* __restrict__ bias,
                                             const float* __restrict__ x1,
                                             float* __restrict__ xout, int N) {
    int lane = threadIdx.x & 63;
    int c = blockIdx.x * 4 + (threadIdx.x >> 6);
    if (c >= N) return;
    float acc = z[(size_t)c * 64 + lane];
    int s = offs[c], e = offs[c + 1];
    for (int j0 = s; j0 < e; j0 += 64) {
        int cnt = e - j0;
        if (cnt > 64) cnt = 64;
        int idx = (j0 + lane < e) ? csr[j0 + lane] : 0;
        for (int d = 0; d < cnt; ++d) {
            int r = __shfl(idx, d, 64);
            acc += z[(size_t)r * 64 + lane];
        }
    }
    xout[(size_t)c * 64 + lane] = dinv[c] * acc + bias[lane] + x1[(size_t)c * 64 + lane];
}

// ---------------------------------------------------------------------------
// head (unchanged)
__global__ __launch_bounds__(256) void k_head(const float* __restrict__ xin,
                                              const float* __restrict__ Wo1,
                                              const float* __restrict__ bo1,
                                              const float* __restrict__ Wo2,
                                              const float* __restrict__ bo2,
                                              float* __restrict__ out, int N) {
    __shared__ float xsg[64][65];
    __shared__ float wg[64][65];
    __shared__ float hs[64][65];
    __shared__ float wo2[128];
    const int tid = threadIdx.x;
    const int n0 = blockIdx.x * 64;
#pragma unroll
    for (int v = 0; v < 4; ++v) {
        int idx = tid + v * 256;
        int n = idx >> 4;
        int jj = (idx & 15) << 2;
        float4 xv = make_float4(0.f, 0.f, 0.f, 0.f);
        if (n0 + n < N) xv = *reinterpret_cast<const float4*>(xin + (size_t)(n0 + n) * 64 + jj);
        xsg[n][jj] = xv.x; xsg[n][jj + 1] = xv.y; xsg[n][jj + 2] = xv.z; xsg[n][jj + 3] = xv.w;
        float4 w = *reinterpret_cast<const float4*>(Wo1 + (size_t)n * 64 + jj);
        wg[n][jj] = w.x; wg[n][jj + 1] = w.y; wg[n][jj + 2] = w.z; wg[n][jj + 3] = w.w;
    }
    if (tid < 128) wo2[tid] = Wo2[tid];
    __syncthreads();
    int j = tid & 63;
    int g = tid >> 6;
    float bj = bo1[j];
    for (int i = 0; i < 16; ++i) {
        int n = g * 16 + i;
        float a = bj;
#pragma unroll
        for (int k = 0; k < 64; ++k) a += xsg[n][k] * wg[k][j];
        hs[n][j] = leaky(a);
    }
    __syncthreads();
    if (tid < 128) {
        int n = tid >> 1;
        int j2 = tid & 1;
        float a = bo2[j2];
#pragma unroll
        for (int k = 0; k < 64; ++k) a += hs[n][k] * wo2[k * 2 + j2];
        if (n0 + n < N) out[(size_t)(n0 + n) * 2 + j2] = 1.f / (1.f + expf(-a));
    }
}

// ---------------------------------------------------------------------------
extern "C" void kernel_launch(void* const* d_in, const int* in_sizes, int n_in,
                              void* d_out, int out_size, void* d_ws, size_t ws_size,
                              hipStream_t stream) {
    const float* screen   = (const float*)d_in[0];
    const float* des      = (const float*)d_in[1];
    const float* tweet    = (const float*)d_in[2];
    const float* profile  = (const float*)d_in[3];
    const float* personal = (const float*)d_in[4];
    const int*   edge     = (const int*)d_in[5];
    const float* Ws  = (const float*)d_in[6],  *bs  = (const float*)d_in[7];
    const float* Wd  = (const float*)d_in[8],  *bd  = (const float*)d_in[9];
    const float* Wt  = (const float*)d_in[10], *bt  = (const float*)d_in[11];
    const float* Wp  = (const float*)d_in[12], *bp  = (const float*)d_in[13];
    const float* Wpe = (const float*)d_in[14], *bpe = (const float*)d_in[15];
    const float* Wl  = (const float*)d_in[16], *bl  = (const float*)d_in[17];
    const float* Wg1 = (const float*)d_in[18], *bg1 = (const float*)d_in[19];
    const float* Wg2 = (const float*)d_in[20], *bg2 = (const float*)d_in[21];
    const float* Wg3 = (const float*)d_in[22], *bg3 = (const float*)d_in[23];
    const float* Wo1 = (const float*)d_in[24], *bo1 = (const float*)d_in[25];
    const float* Wo2 = (const float*)d_in[26], *bo2 = (const float*)d_in[27];

    const int N = in_sizes[0] / 768;   // 50000
    const int E = in_sizes[5] / 2;     // 1600000
    const int* row = edge;
    const int* col = edge + E;

    size_t off = 0;
    auto alloc = [&](size_t bytes) -> void* {
        void* p = (char*)d_ws + off;
        off += (bytes + 255) & ~(size_t)255;
        return p;
    };
    const size_t NF = (size_t)N * 64;
    float* x1   = (float*)alloc(NF * 4);
    float* xa   = (float*)alloc(NF * 4);
    float* xb   = (float*)alloc(NF * 4);
    float* z    = (float*)alloc(NF * 4);
    float* dinv = (float*)alloc((size_t)N * 4);
    int* deg  = (int*)alloc((size_t)N * 4);
    int* part = (int*)alloc((size_t)N * 4);
    int* offs = (int*)alloc((size_t)(N + 1) * 4);
    int* pos  = (int*)alloc((size_t)N * 4);
    int* csr  = (int*)alloc((size_t)E * 4);
    const int NB = (N + 255) / 256;
    int* bsum = (int*)alloc((size_t)NB * 4);
    int* boff = (int*)alloc((size_t)NB * 4);
    (void)ws_size; (void)n_in; (void)out_size;

    // CSR build
    hipMemsetAsync(deg, 0, (size_t)N * 4, stream);
    k_deg<<<(E + 255) / 256, 256, 0, stream>>>(col, E, deg);
    k_scan_part<<<NB, 256, 0, stream>>>(deg, part, bsum, N);
    k_scan_sums<<<1, 256, 0, stream>>>(bsum, boff, NB, offs + N);
    k_scan_final<<<NB, 256, 0, stream>>>(part, boff, deg, offs, pos, dinv, N);
    k_fill<<<(E + 255) / 256, 256, 0, stream>>>(row, col, E, pos, csr);

    // Phase A: big feature linears (128-node tiles, 3 features in one grid)
    const int NG2 = (N + 127) / 128;
    k_featB<<<NG2 * 3, 256, 0, stream>>>(screen, des, tweet, Ws, bs, Wd, bd, Wt, bt, x1, N, NG2);
    k_small<<<(N + 255) / 256, 256, 0, stream>>>(profile, personal, Wp, bp, Wpe, bpe, x1, N);

    const int NGB = (N + 63) / 64;
    // x = leaky(x1 @ Wl + bl)
    k_mm64<<<NGB, 256, 0, stream>>>(x1, Wl, bl, nullptr, 1, xa, N);

    const int NAB = (N + 3) / 4;
    // layer 1
    k_mm64<<<NGB, 256, 0, stream>>>(xa, Wg1, nullptr, dinv, 0, z, N);
    k_agg<<<NAB, 256, 0, stream>>>(z, offs, csr, dinv, bg1, x1, xb, N);
    // layer 2
    k_mm64<<<NGB, 256, 0, stream>>>(xb, Wg2, nullptr, dinv, 0, z, N);
    k_agg<<<NAB, 256, 0, stream>>>(z, offs, csr, dinv, bg2, x1, xa, N);
    // layer 3
    k_mm64<<<NGB, 256, 0, stream>>>(xa, Wg3, nullptr, dinv, 0, z, N);
    k_agg<<<NAB, 256, 0, stream>>>(z, offs, csr, dinv, bg3, x1, xb, N);

    // head
    k_head<<<NGB, 256, 0, stream>>>(xb, Wo1, bo1, Wo2, bo2, (float*)d_out, N);
}

// Round 4
// 565.415 us; speedup vs baseline: 2.0935x; 1.2218x over previous
//
#include <hip/hip_runtime.h>

__device__ __forceinline__ float leaky(float v) { return v >= 0.f ? v : 0.01f * v; }

__device__ __forceinline__ void fma4(float4& a, float s, const float4& w) {
    a.x = fmaf(s, w.x, a.x); a.y = fmaf(s, w.y, a.y);
    a.z = fmaf(s, w.z, a.z); a.w = fmaf(s, w.w, a.w);
}

#define GLOAD_LDS16(gp, lp) \
    __builtin_amdgcn_global_load_lds( \
        (const __attribute__((address_space(1))) void*)(gp), \
        (__attribute__((address_space(3))) void*)(lp), 16, 0, 0)

// ---------------------------------------------------------------------------
// CSR build (unchanged)
__global__ void k_deg(const int* __restrict__ col, int E, int* __restrict__ deg) {
    int e = blockIdx.x * blockDim.x + threadIdx.x;
    if (e < E) atomicAdd(&deg[col[e]], 1);
}

__global__ __launch_bounds__(256) void k_scan_part(const int* __restrict__ deg,
                                                   int* __restrict__ part,
                                                   int* __restrict__ bsum, int N) {
    __shared__ int tmp[256];
    int tid = threadIdx.x;
    int i = blockIdx.x * 256 + tid;
    int v = (i < N) ? deg[i] : 0;
    tmp[tid] = v;
    __syncthreads();
    for (int ofs = 1; ofs < 256; ofs <<= 1) {
        int t = (tid >= ofs) ? tmp[tid - ofs] : 0;
        __syncthreads();
        tmp[tid] += t;
        __syncthreads();
    }
    int incl = tmp[tid];
    if (i < N) part[i] = incl - v;
    if (tid == 255) bsum[blockIdx.x] = incl;
}

__global__ __launch_bounds__(256) void k_scan_sums(const int* __restrict__ bsum,
                                                   int* __restrict__ boff, int NB,
                                                   int* __restrict__ offs_last) {
    __shared__ int tmp[256];
    int tid = threadIdx.x;
    int v = (tid < NB) ? bsum[tid] : 0;
    tmp[tid] = v;
    __syncthreads();
    for (int ofs = 1; ofs < 256; ofs <<= 1) {
        int t = (tid >= ofs) ? tmp[tid - ofs] : 0;
        __syncthreads();
        tmp[tid] += t;
        __syncthreads();
    }
    int incl = tmp[tid];
    if (tid < NB) boff[tid] = incl - v;
    if (tid == 255) offs_last[0] = incl;
}

__global__ __launch_bounds__(256) void k_scan_final(const int* __restrict__ part,
                                                    const int* __restrict__ boff,
                                                    const int* __restrict__ deg,
                                                    int* __restrict__ offs,
                                                    int* __restrict__ pos,
                                                    float* __restrict__ dinv, int N) {
    int i = blockIdx.x * 256 + threadIdx.x;
    if (i < N) {
        int o = part[i] + boff[blockIdx.x];
        offs[i] = o;
        pos[i] = o;
        dinv[i] = rsqrtf((float)(deg[i] + 1));
    }
}

__global__ void k_fill(const int* __restrict__ row, const int* __restrict__ col, int E,
                       int* __restrict__ pos, int* __restrict__ csr) {
    int e = blockIdx.x * blockDim.x + threadIdx.x;
    if (e < E) {
        int p = atomicAdd(&pos[col[e]], 1);
        csr[p] = row[e];
    }
}

// ---------------------------------------------------------------------------
// Phase A (unchanged from R3): global_load_lds staging, pre-swizzled source.
__global__ __attribute__((amdgpu_waves_per_eu(4, 4))) __launch_bounds__(256)
void k_featB(
    const float* __restrict__ s, const float* __restrict__ d, const float* __restrict__ t,
    const float* __restrict__ Ws, const float* __restrict__ bs2,
    const float* __restrict__ Wd, const float* __restrict__ bd2,
    const float* __restrict__ Wt, const float* __restrict__ bt2,
    float* __restrict__ x1g, int N, int NG) {
    __shared__ float4 smem[2304];  // [2][1024] xs + [2][128] ws = 36 KB

    const int bid = blockIdx.x;
    const int f = bid / NG;
    const int grp = bid - f * NG;
    const float* __restrict__ X = (f == 0) ? s : ((f == 1) ? d : t);
    const float* __restrict__ W = (f == 0) ? Ws : ((f == 1) ? Wd : Wt);
    const float* __restrict__ B = (f == 0) ? bs2 : ((f == 1) ? bd2 : bt2);
    const int n0 = grp * 128;
    const int tid = threadIdx.x;
    const int lane = tid & 63;
    const int wid = tid >> 6;
    const int kq = wid;
    const int nq = lane & 15;
    const int jq = lane >> 4;

    auto stage = [&](int c, int b) {
        float4* xs4 = smem + b * 1024;
        float4* ws4 = smem + 2048 + b * 128;
#pragma unroll
        for (int v = 0; v < 4; ++v) {
            int L = wid * 256 + v * 64 + lane;
            int n = L >> 3, ss = L & 7;
            int c4 = ss ^ (n & 7);
            int nn = n0 + n; if (nn >= N) nn = N - 1;
            const float* g = X + (size_t)nn * 768 + c * 32 + c4 * 4;
            GLOAD_LDS16(g, xs4 + wid * 256 + v * 64);
        }
        if (wid < 2) {
            const float* g = W + (size_t)c * 512 + ((wid & 1) * 64 + lane) * 4;
            GLOAD_LDS16(g, ws4 + (wid & 1) * 64);
        }
    };

    float4 acc[8];
#pragma unroll
    for (int g = 0; g < 8; ++g) acc[g] = make_float4(0.f, 0.f, 0.f, 0.f);

    stage(0, 0);
    __syncthreads();

    for (int c = 0; c < 24; ++c) {
        const int b = c & 1;
        if (c < 23) stage(c + 1, b ^ 1);
        const float4* xs4 = smem + b * 1024;
        const float4* ws4 = smem + 2048 + b * 128;
#pragma unroll
        for (int step = 0; step < 2; ++step) {
            int k = kq * 8 + step * 4;
            float4 w0 = ws4[(k + 0) * 4 + jq];
            float4 w1 = ws4[(k + 1) * 4 + jq];
            float4 w2 = ws4[(k + 2) * 4 + jq];
            float4 w3 = ws4[(k + 3) * 4 + jq];
            int k4 = k >> 2;
#pragma unroll
            for (int g = 0; g < 8; ++g) {
                int n = nq + (g << 4);
                float4 xv = xs4[n * 8 + (k4 ^ (n & 7))];
                fma4(acc[g], xv.x, w0);
                fma4(acc[g], xv.y, w1);
                fma4(acc[g], xv.z, w2);
                fma4(acc[g], xv.w, w3);
            }
        }
        __syncthreads();
    }

    float4* red4 = smem;
#pragma unroll
    for (int g = 0; g < 8; ++g)
        red4[lane * 33 + g * 4 + kq] = acc[g];
    __syncthreads();

    float4 bq[4];
#pragma unroll
    for (int j4 = 0; j4 < 4; ++j4) bq[j4] = *reinterpret_cast<const float4*>(B + j4 * 4);

#pragma unroll
    for (int half = 0; half < 2; ++half) {
        int idx = half * 256 + tid;
        int lane_r = idx & 63;
        int g_r = idx >> 6;
        float4 a0 = red4[lane_r * 33 + g_r * 4 + 0];
        float4 a1 = red4[lane_r * 33 + g_r * 4 + 1];
        float4 a2 = red4[lane_r * 33 + g_r * 4 + 2];
        float4 a3 = red4[lane_r * 33 + g_r * 4 + 3];
        int j4 = lane_r >> 4;
        float4 bb = bq[j4];
        float4 r;
        r.x = leaky(a0.x + a1.x + a2.x + a3.x + bb.x);
        r.y = leaky(a0.y + a1.y + a2.y + a3.y + bb.y);
        r.z = leaky(a0.z + a1.z + a2.z + a3.z + bb.z);
        r.w = leaky(a0.w + a1.w + a2.w + a3.w + bb.w);
        int n = (lane_r & 15) + (g_r << 4);
        if (n0 + n < N)
            *reinterpret_cast<float4*>(x1g + (size_t)(n0 + n) * 64 + f * 16 + j4 * 4) = r;
    }
}

// ---------------------------------------------------------------------------
// Tiny linears (unchanged)
__global__ __launch_bounds__(256) void k_small(const float* __restrict__ prof,
                                               const float* __restrict__ pers,
                                               const float* __restrict__ Wp, const float* __restrict__ bp,
                                               const float* __restrict__ Wpe, const float* __restrict__ bpe,
                                               float* __restrict__ x1g, int N) {
    int n = blockIdx.x * blockDim.x + threadIdx.x;
    if (n >= N) return;
    float pv[5], pe[7];
#pragma unroll
    for (int i = 0; i < 5; ++i) pv[i] = prof[(size_t)n * 5 + i];
#pragma unroll
    for (int i = 0; i < 7; ++i) pe[i] = pers[(size_t)n * 7 + i];
    float o[16];
#pragma unroll
    for (int j = 0; j < 8; ++j) {
        float a = bp[j];
#pragma unroll
        for (int i = 0; i < 5; ++i) a = fmaf(pv[i], Wp[i * 8 + j], a);
        o[j] = leaky(a);
        float a2 = bpe[j];
#pragma unroll
        for (int i = 0; i < 7; ++i) a2 = fmaf(pe[i], Wpe[i * 8 + j], a2);
        o[8 + j] = leaky(a2);
    }
#pragma unroll
    for (int v = 0; v < 4; ++v)
        *reinterpret_cast<float4*>(x1g + (size_t)n * 64 + 48 + v * 4) =
            make_float4(o[v * 4], o[v * 4 + 1], o[v * 4 + 2], o[v * 4 + 3]);
}

// ---------------------------------------------------------------------------
// Generic 64x64 node-matmul (unchanged)
__global__ __launch_bounds__(256, 4) void k_mm64(const float* __restrict__ xin,
                                                 const float* __restrict__ W,
                                                 const float* __restrict__ bias,
                                                 const float* __restrict__ dinvv,
                                                 int act,
                                                 float* __restrict__ out, int N) {
    __shared__ float4 xt4[1024];  // [64][16] swizzled
    __shared__ float4 wt4[1024];  // [64 k][16 j4] linear
    const int tid = threadIdx.x;
    const int n0 = blockIdx.x * 64;
#pragma unroll
    for (int v = 0; v < 4; ++v) {
        int L = v * 256 + tid;
        int n = L >> 4, c4 = L & 15;
        int nn = n0 + n; if (nn >= N) nn = N - 1;
        xt4[n * 16 + (c4 ^ (n & 15))] = *reinterpret_cast<const float4*>(xin + (size_t)nn * 64 + c4 * 4);
        wt4[L] = *reinterpret_cast<const float4*>(W + (size_t)L * 4);
    }
    __syncthreads();
    const int nq = tid & 15;
    const int jq = tid >> 4;  // 0..15
    float4 acc[4];
#pragma unroll
    for (int g = 0; g < 4; ++g) acc[g] = make_float4(0.f, 0.f, 0.f, 0.f);
    for (int k = 0; k < 64; k += 4) {
        float4 w0 = wt4[(k + 0) * 16 + jq];
        float4 w1 = wt4[(k + 1) * 16 + jq];
        float4 w2 = wt4[(k + 2) * 16 + jq];
        float4 w3 = wt4[(k + 3) * 16 + jq];
        int k4 = k >> 2;
#pragma unroll
        for (int g = 0; g < 4; ++g) {
            int n = nq + (g << 4);
            float4 xv = xt4[n * 16 + (k4 ^ (n & 15))];
            fma4(acc[g], xv.x, w0);
            fma4(acc[g], xv.y, w1);
            fma4(acc[g], xv.z, w2);
            fma4(acc[g], xv.w, w3);
        }
    }
    float4 bb = make_float4(0.f, 0.f, 0.f, 0.f);
    if (bias) bb = *reinterpret_cast<const float4*>(bias + jq * 4);
#pragma unroll
    for (int g = 0; g < 4; ++g) {
        int n = nq + (g << 4);
        if (n0 + n >= N) continue;
        float4 r = acc[g];
        r.x += bb.x; r.y += bb.y; r.z += bb.z; r.w += bb.w;
        if (act) { r.x = leaky(r.x); r.y = leaky(r.y); r.z = leaky(r.z); r.w = leaky(r.w); }
        if (dinvv) {
            float dv = dinvv[n0 + n];
            r.x *= dv; r.y *= dv; r.z *= dv; r.w *= dv;
        }
        *reinterpret_cast<float4*>(out + (size_t)(n0 + n) * 64 + jq * 4) = r;
    }
}

// ---------------------------------------------------------------------------
// Gather aggregation — REWORKED: scalar (uniform) CSR index loads, 8-deep
// independent gather unroll for memory-level parallelism.
__global__ __launch_bounds__(256) void k_agg(const float* __restrict__ z,
                                             const int* __restrict__ offs,
                                             const int* __restrict__ csr,
                                             const float* __restrict__ dinv,
                                             const float* __restrict__ bias,
                                             const float* __restrict__ x1,
                                             float* __restrict__ xout, int N) {
    int lane = threadIdx.x & 63;
    int c = blockIdx.x * 4 + (threadIdx.x >> 6);
    if (c >= N) return;
    // force wave-uniform bounds -> csr[j] becomes scalar (s_load) path
    int s = __builtin_amdgcn_readfirstlane(offs[c]);
    int e = __builtin_amdgcn_readfirstlane(offs[c + 1]);
    const float* zl = z + lane;
    float acc = zl[(size_t)c * 64];  // self-loop term
    float a0 = 0.f, a1 = 0.f, a2 = 0.f, a3 = 0.f;
    float a4 = 0.f, a5 = 0.f, a6 = 0.f, a7 = 0.f;
    int j = s;
    for (; j + 8 <= e; j += 8) {
        int r0 = csr[j + 0], r1 = csr[j + 1], r2 = csr[j + 2], r3 = csr[j + 3];
        int r4 = csr[j + 4], r5 = csr[j + 5], r6 = csr[j + 6], r7 = csr[j + 7];
        a0 += zl[(size_t)r0 * 64];
        a1 += zl[(size_t)r1 * 64];
        a2 += zl[(size_t)r2 * 64];
        a3 += zl[(size_t)r3 * 64];
        a4 += zl[(size_t)r4 * 64];
        a5 += zl[(size_t)r5 * 64];
        a6 += zl[(size_t)r6 * 64];
        a7 += zl[(size_t)r7 * 64];
    }
    for (; j < e; ++j) acc += zl[(size_t)csr[j] * 64];
    acc += ((a0 + a1) + (a2 + a3)) + ((a4 + a5) + (a6 + a7));
    xout[(size_t)c * 64 + lane] = dinv[c] * acc + bias[lane] + x1[(size_t)c * 64 + lane];
}

// ---------------------------------------------------------------------------
// head (unchanged)
__global__ __launch_bounds__(256) void k_head(const float* __restrict__ xin,
                                              const float* __restrict__ Wo1,
                                              const float* __restrict__ bo1,
                                              const float* __restrict__ Wo2,
                                              const float* __restrict__ bo2,
                                              float* __restrict__ out, int N) {
    __shared__ float xsg[64][65];
    __shared__ float wg[64][65];
    __shared__ float hs[64][65];
    __shared__ float wo2[128];
    const int tid = threadIdx.x;
    const int n0 = blockIdx.x * 64;
#pragma unroll
    for (int v = 0; v < 4; ++v) {
        int idx = tid + v * 256;
        int n = idx >> 4;
        int jj = (idx & 15) << 2;
        float4 xv = make_float4(0.f, 0.f, 0.f, 0.f);
        if (n0 + n < N) xv = *reinterpret_cast<const float4*>(xin + (size_t)(n0 + n) * 64 + jj);
        xsg[n][jj] = xv.x; xsg[n][jj + 1] = xv.y; xsg[n][jj + 2] = xv.z; xsg[n][jj + 3] = xv.w;
        float4 w = *reinterpret_cast<const float4*>(Wo1 + (size_t)n * 64 + jj);
        wg[n][jj] = w.x; wg[n][jj + 1] = w.y; wg[n][jj + 2] = w.z; wg[n][jj + 3] = w.w;
    }
    if (tid < 128) wo2[tid] = Wo2[tid];
    __syncthreads();
    int j = tid & 63;
    int g = tid >> 6;
    float bj = bo1[j];
    for (int i = 0; i < 16; ++i) {
        int n = g * 16 + i;
        float a = bj;
#pragma unroll
        for (int k = 0; k < 64; ++k) a += xsg[n][k] * wg[k][j];
        hs[n][j] = leaky(a);
    }
    __syncthreads();
    if (tid < 128) {
        int n = tid >> 1;
        int j2 = tid & 1;
        float a = bo2[j2];
#pragma unroll
        for (int k = 0; k < 64; ++k) a += hs[n][k] * wo2[k * 2 + j2];
        if (n0 + n < N) out[(size_t)(n0 + n) * 2 + j2] = 1.f / (1.f + expf(-a));
    }
}

// ---------------------------------------------------------------------------
extern "C" void kernel_launch(void* const* d_in, const int* in_sizes, int n_in,
                              void* d_out, int out_size, void* d_ws, size_t ws_size,
                              hipStream_t stream) {
    const float* screen   = (const float*)d_in[0];
    const float* des      = (const float*)d_in[1];
    const float* tweet    = (const float*)d_in[2];
    const float* profile  = (const float*)d_in[3];
    const float* personal = (const float*)d_in[4];
    const int*   edge     = (const int*)d_in[5];
    const float* Ws  = (const float*)d_in[6],  *bs  = (const float*)d_in[7];
    const float* Wd  = (const float*)d_in[8],  *bd  = (const float*)d_in[9];
    const float* Wt  = (const float*)d_in[10], *bt  = (const float*)d_in[11];
    const float* Wp  = (const float*)d_in[12], *bp  = (const float*)d_in[13];
    const float* Wpe = (const float*)d_in[14], *bpe = (const float*)d_in[15];
    const float* Wl  = (const float*)d_in[16], *bl  = (const float*)d_in[17];
    const float* Wg1 = (const float*)d_in[18], *bg1 = (const float*)d_in[19];
    const float* Wg2 = (const float*)d_in[20], *bg2 = (const float*)d_in[21];
    const float* Wg3 = (const float*)d_in[22], *bg3 = (const float*)d_in[23];
    const float* Wo1 = (const float*)d_in[24], *bo1 = (const float*)d_in[25];
    const float* Wo2 = (const float*)d_in[26], *bo2 = (const float*)d_in[27];

    const int N = in_sizes[0] / 768;   // 50000
    const int E = in_sizes[5] / 2;     // 1600000
    const int* row = edge;
    const int* col = edge + E;

    size_t off = 0;
    auto alloc = [&](size_t bytes) -> void* {
        void* p = (char*)d_ws + off;
        off += (bytes + 255) & ~(size_t)255;
        return p;
    };
    const size_t NF = (size_t)N * 64;
    float* x1   = (float*)alloc(NF * 4);
    float* xa   = (float*)alloc(NF * 4);
    float* xb   = (float*)alloc(NF * 4);
    float* z    = (float*)alloc(NF * 4);
    float* dinv = (float*)alloc((size_t)N * 4);
    int* deg  = (int*)alloc((size_t)N * 4);
    int* part = (int*)alloc((size_t)N * 4);
    int* offs = (int*)alloc((size_t)(N + 1) * 4);
    int* pos  = (int*)alloc((size_t)N * 4);
    int* csr  = (int*)alloc((size_t)E * 4);
    const int NB = (N + 255) / 256;
    int* bsum = (int*)alloc((size_t)NB * 4);
    int* boff = (int*)alloc((size_t)NB * 4);
    (void)ws_size; (void)n_in; (void)out_size;

    // CSR build
    hipMemsetAsync(deg, 0, (size_t)N * 4, stream);
    k_deg<<<(E + 255) / 256, 256, 0, stream>>>(col, E, deg);
    k_scan_part<<<NB, 256, 0, stream>>>(deg, part, bsum, N);
    k_scan_sums<<<1, 256, 0, stream>>>(bsum, boff, NB, offs + N);
    k_scan_final<<<NB, 256, 0, stream>>>(part, boff, deg, offs, pos, dinv, N);
    k_fill<<<(E + 255) / 256, 256, 0, stream>>>(row, col, E, pos, csr);

    // Phase A: big feature linears
    const int NG2 = (N + 127) / 128;
    k_featB<<<NG2 * 3, 256, 0, stream>>>(screen, des, tweet, Ws, bs, Wd, bd, Wt, bt, x1, N, NG2);
    k_small<<<(N + 255) / 256, 256, 0, stream>>>(profile, personal, Wp, bp, Wpe, bpe, x1, N);

    const int NGB = (N + 63) / 64;
    // x = leaky(x1 @ Wl + bl)
    k_mm64<<<NGB, 256, 0, stream>>>(x1, Wl, bl, nullptr, 1, xa, N);

    const int NAB = (N + 3) / 4;
    // layer 1
    k_mm64<<<NGB, 256, 0, stream>>>(xa, Wg1, nullptr, dinv, 0, z, N);
    k_agg<<<NAB, 256, 0, stream>>>(z, offs, csr, dinv, bg1, x1, xb, N);
    // layer 2
    k_mm64<<<NGB, 256, 0, stream>>>(xb, Wg2, nullptr, dinv, 0, z, N);
    k_agg<<<NAB, 256, 0, stream>>>(z, offs, csr, dinv, bg2, x1, xa, N);
    // layer 3
    k_mm64<<<NGB, 256, 0, stream>>>(xa, Wg3, nullptr, dinv, 0, z, N);
    k_agg<<<NAB, 256, 0, stream>>>(z, offs, csr, dinv, bg3, x1, xb, N);

    // head
    k_head<<<NGB, 256, 0, stream>>>(xb, Wo1, bo1, Wo2, bo2, (float*)d_out, N);
}

// Round 5
// 521.485 us; speedup vs baseline: 2.2699x; 1.0842x over previous
//
#include <hip/hip_runtime.h>

__device__ __forceinline__ float leaky(float v) { return v >= 0.f ? v : 0.01f * v; }

__device__ __forceinline__ void fma4(float4& a, float s, const float4& w) {
    a.x = fmaf(s, w.x, a.x); a.y = fmaf(s, w.y, a.y);
    a.z = fmaf(s, w.z, a.z); a.w = fmaf(s, w.w, a.w);
}

__device__ __forceinline__ unsigned short f2bf(float x) {  // RNE
    unsigned b = __float_as_uint(x);
    return (unsigned short)((b + 0x7FFFu + ((b >> 16) & 1u)) >> 16);
}
__device__ __forceinline__ float bf2f(unsigned short u) {
    return __uint_as_float(((unsigned)u) << 16);
}

#define GLOAD_LDS16(gp, lp) \
    __builtin_amdgcn_global_load_lds( \
        (const __attribute__((address_space(1))) void*)(gp), \
        (__attribute__((address_space(3))) void*)(lp), 16, 0, 0)

// ---------------------------------------------------------------------------
// CSR build (unchanged)
__global__ void k_deg(const int* __restrict__ col, int E, int* __restrict__ deg) {
    int e = blockIdx.x * blockDim.x + threadIdx.x;
    if (e < E) atomicAdd(&deg[col[e]], 1);
}

__global__ __launch_bounds__(256) void k_scan_part(const int* __restrict__ deg,
                                                   int* __restrict__ part,
                                                   int* __restrict__ bsum, int N) {
    __shared__ int tmp[256];
    int tid = threadIdx.x;
    int i = blockIdx.x * 256 + tid;
    int v = (i < N) ? deg[i] : 0;
    tmp[tid] = v;
    __syncthreads();
    for (int ofs = 1; ofs < 256; ofs <<= 1) {
        int t = (tid >= ofs) ? tmp[tid - ofs] : 0;
        __syncthreads();
        tmp[tid] += t;
        __syncthreads();
    }
    int incl = tmp[tid];
    if (i < N) part[i] = incl - v;
    if (tid == 255) bsum[blockIdx.x] = incl;
}

__global__ __launch_bounds__(256) void k_scan_sums(const int* __restrict__ bsum,
                                                   int* __restrict__ boff, int NB,
                                                   int* __restrict__ offs_last) {
    __shared__ int tmp[256];
    int tid = threadIdx.x;
    int v = (tid < NB) ? bsum[tid] : 0;
    tmp[tid] = v;
    __syncthreads();
    for (int ofs = 1; ofs < 256; ofs <<= 1) {
        int t = (tid >= ofs) ? tmp[tid - ofs] : 0;
        __syncthreads();
        tmp[tid] += t;
        __syncthreads();
    }
    int incl = tmp[tid];
    if (tid < NB) boff[tid] = incl - v;
    if (tid == 255) offs_last[0] = incl;
}

__global__ __launch_bounds__(256) void k_scan_final(const int* __restrict__ part,
                                                    const int* __restrict__ boff,
                                                    const int* __restrict__ deg,
                                                    int* __restrict__ offs,
                                                    int* __restrict__ pos,
                                                    float* __restrict__ dinv, int N) {
    int i = blockIdx.x * 256 + threadIdx.x;
    if (i < N) {
        int o = part[i] + boff[blockIdx.x];
        offs[i] = o;
        pos[i] = o;
        dinv[i] = rsqrtf((float)(deg[i] + 1));
    }
}

__global__ void k_fill(const int* __restrict__ row, const int* __restrict__ col, int E,
                       int* __restrict__ pos, int* __restrict__ csr) {
    int e = blockIdx.x * blockDim.x + threadIdx.x;
    if (e < E) {
        int p = atomicAdd(&pos[col[e]], 1);
        csr[p] = row[e];
    }
}

// ---------------------------------------------------------------------------
// Phase A: 3-deep LDS pipeline with counted vmcnt (T3/T4). Each stage = 5
// global_load_lds per wave (4 xs full-wave + 1 ws with lanes<32) so vmcnt
// arithmetic is wave-uniform. Never drain vmcnt to 0 inside the loop.
__global__ __launch_bounds__(256) void k_featB(
    const float* __restrict__ s, const float* __restrict__ d, const float* __restrict__ t,
    const float* __restrict__ Ws, const float* __restrict__ bs2,
    const float* __restrict__ Wd, const float* __restrict__ bd2,
    const float* __restrict__ Wt, const float* __restrict__ bt2,
    float* __restrict__ x1g, int N, int NG) {
    __shared__ float4 smem[3456];  // 3x1024 xs + 3x128 ws = 54 KB

    const int bid = blockIdx.x;
    const int f = bid / NG;
    const int grp = bid - f * NG;
    const float* __restrict__ X = (f == 0) ? s : ((f == 1) ? d : t);
    const float* __restrict__ W = (f == 0) ? Ws : ((f == 1) ? Wd : Wt);
    const float* __restrict__ B = (f == 0) ? bs2 : ((f == 1) ? bd2 : bt2);
    const int n0 = grp * 128;
    const int tid = threadIdx.x;
    const int lane = tid & 63;
    const int wid = tid >> 6;
    const int kq = wid;
    const int nq = lane & 15;
    const int jq = lane >> 4;

    auto stage = [&](int c) {
        const int b = c % 3;
        float4* xs4 = smem + b * 1024;
        float4* ws4 = smem + 3072 + b * 128;
#pragma unroll
        for (int v = 0; v < 4; ++v) {
            int L = wid * 256 + v * 64 + lane;
            int n = L >> 3, ss = L & 7;
            int c4 = ss ^ (n & 7);               // inverse-swizzled source col
            int nn = n0 + n; if (nn >= N) nn = N - 1;
            GLOAD_LDS16(X + (size_t)nn * 768 + c * 32 + c4 * 4, xs4 + wid * 256 + v * 64);
        }
        if (lane < 32) {                         // masked: still 1 vmem instr/wave
            GLOAD_LDS16(W + (size_t)c * 512 + (wid * 32 + lane) * 4, ws4 + wid * 32);
        }
    };

    float4 acc[8];
#pragma unroll
    for (int g = 0; g < 8; ++g) acc[g] = make_float4(0.f, 0.f, 0.f, 0.f);

    stage(0);
    stage(1);
    asm volatile("s_waitcnt vmcnt(5)" ::: "memory");  // stage 0 (oldest 5) done
    __builtin_amdgcn_sched_barrier(0);
    __builtin_amdgcn_s_barrier();
    __builtin_amdgcn_sched_barrier(0);

    for (int c = 0; c < 24; ++c) {
        if (c + 2 < 24) stage(c + 2);   // buf (c+2)%3 == (c-1)%3, freed at last barrier
        const int b = c % 3;
        const float4* xs4 = smem + b * 1024;
        const float4* ws4 = smem + 3072 + b * 128;
#pragma unroll
        for (int step = 0; step < 2; ++step) {
            int k = kq * 8 + step * 4;
            float4 w0 = ws4[(k + 0) * 4 + jq];
            float4 w1 = ws4[(k + 1) * 4 + jq];
            float4 w2 = ws4[(k + 2) * 4 + jq];
            float4 w3 = ws4[(k + 3) * 4 + jq];
            int k4 = k >> 2;
#pragma unroll
            for (int g = 0; g < 8; ++g) {
                int n = nq + (g << 4);
                float4 xv = xs4[n * 8 + (k4 ^ (n & 7))];
                fma4(acc[g], xv.x, w0);
                fma4(acc[g], xv.y, w1);
                fma4(acc[g], xv.z, w2);
                fma4(acc[g], xv.w, w3);
            }
        }
        if (c < 23) {
            if (c < 22) { asm volatile("s_waitcnt vmcnt(5)" ::: "memory"); }
            else        { asm volatile("s_waitcnt vmcnt(0)" ::: "memory"); }
            __builtin_amdgcn_sched_barrier(0);
            __builtin_amdgcn_s_barrier();
            __builtin_amdgcn_sched_barrier(0);
        }
    }
    __syncthreads();  // all compute done before smem reuse

    // cross-wave (kq) reduction via LDS: red[lane][g][kq], stride 33
    float4* red4 = smem;
#pragma unroll
    for (int g = 0; g < 8; ++g)
        red4[lane * 33 + g * 4 + kq] = acc[g];
    __syncthreads();

    float4 bq[4];
#pragma unroll
    for (int j4 = 0; j4 < 4; ++j4) bq[j4] = *reinterpret_cast<const float4*>(B + j4 * 4);

#pragma unroll
    for (int half = 0; half < 2; ++half) {
        int idx = half * 256 + tid;
        int lane_r = idx & 63;
        int g_r = idx >> 6;
        float4 a0 = red4[lane_r * 33 + g_r * 4 + 0];
        float4 a1 = red4[lane_r * 33 + g_r * 4 + 1];
        float4 a2 = red4[lane_r * 33 + g_r * 4 + 2];
        float4 a3 = red4[lane_r * 33 + g_r * 4 + 3];
        int j4 = lane_r >> 4;
        float4 bb = bq[j4];
        float4 r;
        r.x = leaky(a0.x + a1.x + a2.x + a3.x + bb.x);
        r.y = leaky(a0.y + a1.y + a2.y + a3.y + bb.y);
        r.z = leaky(a0.z + a1.z + a2.z + a3.z + bb.z);
        r.w = leaky(a0.w + a1.w + a2.w + a3.w + bb.w);
        int n = (lane_r & 15) + (g_r << 4);
        if (n0 + n < N)
            *reinterpret_cast<float4*>(x1g + (size_t)(n0 + n) * 64 + f * 16 + j4 * 4) = r;
    }
}

// ---------------------------------------------------------------------------
// Tiny linears (unchanged)
__global__ __launch_bounds__(256) void k_small(const float* __restrict__ prof,
                                               const float* __restrict__ pers,
                                               const float* __restrict__ Wp, const float* __restrict__ bp,
                                               const float* __restrict__ Wpe, const float* __restrict__ bpe,
                                               float* __restrict__ x1g, int N) {
    int n = blockIdx.x * blockDim.x + threadIdx.x;
    if (n >= N) return;
    float pv[5], pe[7];
#pragma unroll
    for (int i = 0; i < 5; ++i) pv[i] = prof[(size_t)n * 5 + i];
#pragma unroll
    for (int i = 0; i < 7; ++i) pe[i] = pers[(size_t)n * 7 + i];
    float o[16];
#pragma unroll
    for (int j = 0; j < 8; ++j) {
        float a = bp[j];
#pragma unroll
        for (int i = 0; i < 5; ++i) a = fmaf(pv[i], Wp[i * 8 + j], a);
        o[j] = leaky(a);
        float a2 = bpe[j];
#pragma unroll
        for (int i = 0; i < 7; ++i) a2 = fmaf(pe[i], Wpe[i * 8 + j], a2);
        o[8 + j] = leaky(a2);
    }
#pragma unroll
    for (int v = 0; v < 4; ++v)
        *reinterpret_cast<float4*>(x1g + (size_t)n * 64 + 48 + v * 4) =
            make_float4(o[v * 4], o[v * 4 + 1], o[v * 4 + 2], o[v * 4 + 3]);
}

// ---------------------------------------------------------------------------
// Generic 64x64 node-matmul: out = act( xin @ W [+ bias] ) [* dinv]
// tobf16: write bf16 (for the z tensor consumed by the gather kernel).
__global__ __launch_bounds__(256, 4) void k_mm64(const float* __restrict__ xin,
                                                 const float* __restrict__ W,
                                                 const float* __restrict__ bias,
                                                 const float* __restrict__ dinvv,
                                                 int act, int tobf16,
                                                 void* __restrict__ outp, int N) {
    __shared__ float4 xt4[1024];  // [64][16] swizzled
    __shared__ float4 wt4[1024];  // [64 k][16 j4] linear
    const int tid = threadIdx.x;
    const int n0 = blockIdx.x * 64;
#pragma unroll
    for (int v = 0; v < 4; ++v) {
        int L = v * 256 + tid;
        int n = L >> 4, c4 = L & 15;
        int nn = n0 + n; if (nn >= N) nn = N - 1;
        xt4[n * 16 + (c4 ^ (n & 15))] = *reinterpret_cast<const float4*>(xin + (size_t)nn * 64 + c4 * 4);
        wt4[L] = *reinterpret_cast<const float4*>(W + (size_t)L * 4);
    }
    __syncthreads();
    const int nq = tid & 15;
    const int jq = tid >> 4;  // 0..15
    float4 acc[4];
#pragma unroll
    for (int g = 0; g < 4; ++g) acc[g] = make_float4(0.f, 0.f, 0.f, 0.f);
    for (int k = 0; k < 64; k += 4) {
        float4 w0 = wt4[(k + 0) * 16 + jq];
        float4 w1 = wt4[(k + 1) * 16 + jq];
        float4 w2 = wt4[(k + 2) * 16 + jq];
        float4 w3 = wt4[(k + 3) * 16 + jq];
        int k4 = k >> 2;
#pragma unroll
        for (int g = 0; g < 4; ++g) {
            int n = nq + (g << 4);
            float4 xv = xt4[n * 16 + (k4 ^ (n & 15))];
            fma4(acc[g], xv.x, w0);
            fma4(acc[g], xv.y, w1);
            fma4(acc[g], xv.z, w2);
            fma4(acc[g], xv.w, w3);
        }
    }
    float4 bb = make_float4(0.f, 0.f, 0.f, 0.f);
    if (bias) bb = *reinterpret_cast<const float4*>(bias + jq * 4);
#pragma unroll
    for (int g = 0; g < 4; ++g) {
        int n = nq + (g << 4);
        if (n0 + n >= N) continue;
        float4 r = acc[g];
        r.x += bb.x; r.y += bb.y; r.z += bb.z; r.w += bb.w;
        if (act) { r.x = leaky(r.x); r.y = leaky(r.y); r.z = leaky(r.z); r.w = leaky(r.w); }
        if (dinvv) {
            float dv = dinvv[n0 + n];
            r.x *= dv; r.y *= dv; r.z *= dv; r.w *= dv;
        }
        if (tobf16) {
            ushort4 o;
            o.x = f2bf(r.x); o.y = f2bf(r.y); o.z = f2bf(r.z); o.w = f2bf(r.w);
            *reinterpret_cast<ushort4*>((unsigned short*)outp + (size_t)(n0 + n) * 64 + jq * 4) = o;
        } else {
            *reinterpret_cast<float4*>((float*)outp + (size_t)(n0 + n) * 64 + jq * 4) = r;
        }
    }
}

// ---------------------------------------------------------------------------
// Gather aggregation: bf16 z (half the gather bytes), scalar CSR loads,
// 8-deep independent gather unroll.
__global__ __launch_bounds__(256) void k_agg(const unsigned short* __restrict__ z,
                                             const int* __restrict__ offs,
                                             const int* __restrict__ csr,
                                             const float* __restrict__ dinv,
                                             const float* __restrict__ bias,
                                             const float* __restrict__ x1,
                                             float* __restrict__ xout, int N) {
    int lane = threadIdx.x & 63;
    int c = blockIdx.x * 4 + (threadIdx.x >> 6);
    if (c >= N) return;
    int s = __builtin_amdgcn_readfirstlane(offs[c]);
    int e = __builtin_amdgcn_readfirstlane(offs[c + 1]);
    const unsigned short* zl = z + lane;
    float acc = bf2f(zl[(size_t)c * 64]);  // self-loop term
    float a0 = 0.f, a1 = 0.f, a2 = 0.f, a3 = 0.f;
    float a4 = 0.f, a5 = 0.f, a6 = 0.f, a7 = 0.f;
    int j = s;
    for (; j + 8 <= e; j += 8) {
        int r0 = csr[j + 0], r1 = csr[j + 1], r2 = csr[j + 2], r3 = csr[j + 3];
        int r4 = csr[j + 4], r5 = csr[j + 5], r6 = csr[j + 6], r7 = csr[j + 7];
        a0 += bf2f(zl[(size_t)r0 * 64]);
        a1 += bf2f(zl[(size_t)r1 * 64]);
        a2 += bf2f(zl[(size_t)r2 * 64]);
        a3 += bf2f(zl[(size_t)r3 * 64]);
        a4 += bf2f(zl[(size_t)r4 * 64]);
        a5 += bf2f(zl[(size_t)r5 * 64]);
        a6 += bf2f(zl[(size_t)r6 * 64]);
        a7 += bf2f(zl[(size_t)r7 * 64]);
    }
    for (; j < e; ++j) acc += bf2f(zl[(size_t)csr[j] * 64]);
    acc += ((a0 + a1) + (a2 + a3)) + ((a4 + a5) + (a6 + a7));
    xout[(size_t)c * 64 + lane] = dinv[c] * acc + bias[lane] + x1[(size_t)c * 64 + lane];
}

// ---------------------------------------------------------------------------
// head (unchanged)
__global__ __launch_bounds__(256) void k_head(const float* __restrict__ xin,
                                              const float* __restrict__ Wo1,
                                              const float* __restrict__ bo1,
                                              const float* __restrict__ Wo2,
                                              const float* __restrict__ bo2,
                                              float* __restrict__ out, int N) {
    __shared__ float xsg[64][65];
    __shared__ float wg[64][65];
    __shared__ float hs[64][65];
    __shared__ float wo2[128];
    const int tid = threadIdx.x;
    const int n0 = blockIdx.x * 64;
#pragma unroll
    for (int v = 0; v < 4; ++v) {
        int idx = tid + v * 256;
        int n = idx >> 4;
        int jj = (idx & 15) << 2;
        float4 xv = make_float4(0.f, 0.f, 0.f, 0.f);
        if (n0 + n < N) xv = *reinterpret_cast<const float4*>(xin + (size_t)(n0 + n) * 64 + jj);
        xsg[n][jj] = xv.x; xsg[n][jj + 1] = xv.y; xsg[n][jj + 2] = xv.z; xsg[n][jj + 3] = xv.w;
        float4 w = *reinterpret_cast<const float4*>(Wo1 + (size_t)n * 64 + jj);
        wg[n][jj] = w.x; wg[n][jj + 1] = w.y; wg[n][jj + 2] = w.z; wg[n][jj + 3] = w.w;
    }
    if (tid < 128) wo2[tid] = Wo2[tid];
    __syncthreads();
    int j = tid & 63;
    int g = tid >> 6;
    float bj = bo1[j];
    for (int i = 0; i < 16; ++i) {
        int n = g * 16 + i;
        float a = bj;
#pragma unroll
        for (int k = 0; k < 64; ++k) a += xsg[n][k] * wg[k][j];
        hs[n][j] = leaky(a);
    }
    __syncthreads();
    if (tid < 128) {
        int n = tid >> 1;
        int j2 = tid & 1;
        float a = bo2[j2];
#pragma unroll
        for (int k = 0; k < 64; ++k) a += hs[n][k] * wo2[k * 2 + j2];
        if (n0 + n < N) out[(size_t)(n0 + n) * 2 + j2] = 1.f / (1.f + expf(-a));
    }
}

// ---------------------------------------------------------------------------
extern "C" void kernel_launch(void* const* d_in, const int* in_sizes, int n_in,
                              void* d_out, int out_size, void* d_ws, size_t ws_size,
                              hipStream_t stream) {
    const float* screen   = (const float*)d_in[0];
    const float* des      = (const float*)d_in[1];
    const float* tweet    = (const float*)d_in[2];
    const float* profile  = (const float*)d_in[3];
    const float* personal = (const float*)d_in[4];
    const int*   edge     = (const int*)d_in[5];
    const float* Ws  = (const float*)d_in[6],  *bs  = (const float*)d_in[7];
    const float* Wd  = (const float*)d_in[8],  *bd  = (const float*)d_in[9];
    const float* Wt  = (const float*)d_in[10], *bt  = (const float*)d_in[11];
    const float* Wp  = (const float*)d_in[12], *bp  = (const float*)d_in[13];
    const float* Wpe = (const float*)d_in[14], *bpe = (const float*)d_in[15];
    const float* Wl  = (const float*)d_in[16], *bl  = (const float*)d_in[17];
    const float* Wg1 = (const float*)d_in[18], *bg1 = (const float*)d_in[19];
    const float* Wg2 = (const float*)d_in[20], *bg2 = (const float*)d_in[21];
    const float* Wg3 = (const float*)d_in[22], *bg3 = (const float*)d_in[23];
    const float* Wo1 = (const float*)d_in[24], *bo1 = (const float*)d_in[25];
    const float* Wo2 = (const float*)d_in[26], *bo2 = (const float*)d_in[27];

    const int N = in_sizes[0] / 768;   // 50000
    const int E = in_sizes[5] / 2;     // 1600000
    const int* row = edge;
    const int* col = edge + E;

    size_t off = 0;
    auto alloc = [&](size_t bytes) -> void* {
        void* p = (char*)d_ws + off;
        off += (bytes + 255) & ~(size_t)255;
        return p;
    };
    const size_t NF = (size_t)N * 64;
    float* x1   = (float*)alloc(NF * 4);
    float* xa   = (float*)alloc(NF * 4);
    float* xb   = (float*)alloc(NF * 4);
    unsigned short* z = (unsigned short*)alloc(NF * 2);
    float* dinv = (float*)alloc((size_t)N * 4);
    int* deg  = (int*)alloc((size_t)N * 4);
    int* part = (int*)alloc((size_t)N * 4);
    int* offs = (int*)alloc((size_t)(N + 1) * 4);
    int* pos  = (int*)alloc((size_t)N * 4);
    int* csr  = (int*)alloc((size_t)E * 4);
    const int NB = (N + 255) / 256;
    int* bsum = (int*)alloc((size_t)NB * 4);
    int* boff = (int*)alloc((size_t)NB * 4);
    (void)ws_size; (void)n_in; (void)out_size;

    // CSR build
    hipMemsetAsync(deg, 0, (size_t)N * 4, stream);
    k_deg<<<(E + 255) / 256, 256, 0, stream>>>(col, E, deg);
    k_scan_part<<<NB, 256, 0, stream>>>(deg, part, bsum, N);
    k_scan_sums<<<1, 256, 0, stream>>>(bsum, boff, NB, offs + N);
    k_scan_final<<<NB, 256, 0, stream>>>(part, boff, deg, offs, pos, dinv, N);
    k_fill<<<(E + 255) / 256, 256, 0, stream>>>(row, col, E, pos, csr);

    // Phase A: big feature linears
    const int NG2 = (N + 127) / 128;
    k_featB<<<NG2 * 3, 256, 0, stream>>>(screen, des, tweet, Ws, bs, Wd, bd, Wt, bt, x1, N, NG2);
    k_small<<<(N + 255) / 256, 256, 0, stream>>>(profile, personal, Wp, bp, Wpe, bpe, x1, N);

    const int NGB = (N + 63) / 64;
    // x = leaky(x1 @ Wl + bl)
    k_mm64<<<NGB, 256, 0, stream>>>(x1, Wl, bl, nullptr, 1, 0, xa, N);

    const int NAB = (N + 3) / 4;
    // layer 1
    k_mm64<<<NGB, 256, 0, stream>>>(xa, Wg1, nullptr, dinv, 0, 1, z, N);
    k_agg<<<NAB, 256, 0, stream>>>(z, offs, csr, dinv, bg1, x1, xb, N);
    // layer 2
    k_mm64<<<NGB, 256, 0, stream>>>(xb, Wg2, nullptr, dinv, 0, 1, z, N);
    k_agg<<<NAB, 256, 0, stream>>>(z, offs, csr, dinv, bg2, x1, xa, N);
    // layer 3
    k_mm64<<<NGB, 256, 0, stream>>>(xa, Wg3, nullptr, dinv, 0, 1, z, N);
    k_agg<<<NAB, 256, 0, stream>>>(z, offs, csr, dinv, bg3, x1, xb, N);

    // head
    k_head<<<NGB, 256, 0, stream>>>(xb, Wo1, bo1, Wo2, bo2, (float*)d_out, N);
}

// Round 6
// 502.893 us; speedup vs baseline: 2.3538x; 1.0370x over previous
//
#include <hip/hip_runtime.h>

__device__ __forceinline__ float leaky(float v) { return v >= 0.f ? v : 0.01f * v; }

__device__ __forceinline__ void fma4(float4& a, float s, const float4& w) {
    a.x = fmaf(s, w.x, a.x); a.y = fmaf(s, w.y, a.y);
    a.z = fmaf(s, w.z, a.z); a.w = fmaf(s, w.w, a.w);
}

__device__ __forceinline__ unsigned short f2bf(float x) {  // RNE
    unsigned b = __float_as_uint(x);
    return (unsigned short)((b + 0x7FFFu + ((b >> 16) & 1u)) >> 16);
}
__device__ __forceinline__ float bf2f(unsigned short u) {
    return __uint_as_float(((unsigned)u) << 16);
}

#define GLOAD_LDS16(gp, lp) \
    __builtin_amdgcn_global_load_lds( \
        (const __attribute__((address_space(1))) void*)(gp), \
        (__attribute__((address_space(3))) void*)(lp), 16, 0, 0)

// ---------------------------------------------------------------------------
// CSR build (unchanged)
__global__ void k_deg(const int* __restrict__ col, int E, int* __restrict__ deg) {
    int e = blockIdx.x * blockDim.x + threadIdx.x;
    if (e < E) atomicAdd(&deg[col[e]], 1);
}

__global__ __launch_bounds__(256) void k_scan_part(const int* __restrict__ deg,
                                                   int* __restrict__ part,
                                                   int* __restrict__ bsum, int N) {
    __shared__ int tmp[256];
    int tid = threadIdx.x;
    int i = blockIdx.x * 256 + tid;
    int v = (i < N) ? deg[i] : 0;
    tmp[tid] = v;
    __syncthreads();
    for (int ofs = 1; ofs < 256; ofs <<= 1) {
        int t = (tid >= ofs) ? tmp[tid - ofs] : 0;
        __syncthreads();
        tmp[tid] += t;
        __syncthreads();
    }
    int incl = tmp[tid];
    if (i < N) part[i] = incl - v;
    if (tid == 255) bsum[blockIdx.x] = incl;
}

__global__ __launch_bounds__(256) void k_scan_sums(const int* __restrict__ bsum,
                                                   int* __restrict__ boff, int NB,
                                                   int* __restrict__ offs_last) {
    __shared__ int tmp[256];
    int tid = threadIdx.x;
    int v = (tid < NB) ? bsum[tid] : 0;
    tmp[tid] = v;
    __syncthreads();
    for (int ofs = 1; ofs < 256; ofs <<= 1) {
        int t = (tid >= ofs) ? tmp[tid - ofs] : 0;
        __syncthreads();
        tmp[tid] += t;
        __syncthreads();
    }
    int incl = tmp[tid];
    if (tid < NB) boff[tid] = incl - v;
    if (tid == 255) offs_last[0] = incl;
}

__global__ __launch_bounds__(256) void k_scan_final(const int* __restrict__ part,
                                                    const int* __restrict__ boff,
                                                    const int* __restrict__ deg,
                                                    int* __restrict__ offs,
                                                    int* __restrict__ pos,
                                                    float* __restrict__ dinv, int N) {
    int i = blockIdx.x * 256 + threadIdx.x;
    if (i < N) {
        int o = part[i] + boff[blockIdx.x];
        offs[i] = o;
        pos[i] = o;
        dinv[i] = rsqrtf((float)(deg[i] + 1));
    }
}

__global__ void k_fill(const int* __restrict__ row, const int* __restrict__ col, int E,
                       int* __restrict__ pos, int* __restrict__ csr) {
    int e = blockIdx.x * blockDim.x + threadIdx.x;
    if (e < E) {
        int p = atomicAdd(&pos[col[e]], 1);
        csr[p] = row[e];
    }
}

// ---------------------------------------------------------------------------
// Phase A: 64-node tiles (x2346 blocks), 3-deep counted-vmcnt pipeline,
// 30 KB LDS -> 5 blocks/CU. Stage = 3 wave-uniform global_load_lds.
// Tail blocks (bid >= 3*NG) run the fused profile/personal tiny linears.
__global__ __launch_bounds__(256) void k_featB(
    const float* __restrict__ s, const float* __restrict__ d, const float* __restrict__ t,
    const float* __restrict__ Ws, const float* __restrict__ bs2,
    const float* __restrict__ Wd, const float* __restrict__ bd2,
    const float* __restrict__ Wt, const float* __restrict__ bt2,
    const float* __restrict__ prof, const float* __restrict__ pers,
    const float* __restrict__ Wp, const float* __restrict__ bp,
    const float* __restrict__ Wpe, const float* __restrict__ bpe,
    float* __restrict__ x1g, int N, int NG) {
    __shared__ float4 smem[1920];  // 3 x (512 xs + 128 ws) = 30 KB

    const int bid = blockIdx.x;
    const int tid = threadIdx.x;

    if (bid >= 3 * NG) {  // ---- fused tiny linears ----
        int n = (bid - 3 * NG) * 256 + tid;
        if (n >= N) return;
        float pv[5], pe[7];
#pragma unroll
        for (int i = 0; i < 5; ++i) pv[i] = prof[(size_t)n * 5 + i];
#pragma unroll
        for (int i = 0; i < 7; ++i) pe[i] = pers[(size_t)n * 7 + i];
        float o[16];
#pragma unroll
        for (int j = 0; j < 8; ++j) {
            float a = bp[j];
#pragma unroll
            for (int i = 0; i < 5; ++i) a = fmaf(pv[i], Wp[i * 8 + j], a);
            o[j] = leaky(a);
            float a2 = bpe[j];
#pragma unroll
            for (int i = 0; i < 7; ++i) a2 = fmaf(pe[i], Wpe[i * 8 + j], a2);
            o[8 + j] = leaky(a2);
        }
#pragma unroll
        for (int v = 0; v < 4; ++v)
            *reinterpret_cast<float4*>(x1g + (size_t)n * 64 + 48 + v * 4) =
                make_float4(o[v * 4], o[v * 4 + 1], o[v * 4 + 2], o[v * 4 + 3]);
        return;
    }

    const int f = bid / NG;
    const int grp = bid - f * NG;
    const float* __restrict__ X = (f == 0) ? s : ((f == 1) ? d : t);
    const float* __restrict__ W = (f == 0) ? Ws : ((f == 1) ? Wd : Wt);
    const float* __restrict__ B = (f == 0) ? bs2 : ((f == 1) ? bd2 : bt2);
    const int n0 = grp * 64;
    const int lane = tid & 63;
    const int wid = tid >> 6;
    const int kq = wid;
    const int nq = lane & 15;
    const int jq = lane >> 4;

    auto stage = [&](int c) {
        const int b = c % 3;
        float4* xs4 = smem + b * 512;
        float4* ws4 = smem + 1536 + b * 128;
#pragma unroll
        for (int v = 0; v < 2; ++v) {
            int L = wid * 128 + v * 64 + lane;
            int n = L >> 3, ss = L & 7;
            int c4 = ss ^ (n & 7);               // inverse-swizzled source col
            int nn = n0 + n; if (nn >= N) nn = N - 1;
            GLOAD_LDS16(X + (size_t)nn * 768 + c * 32 + c4 * 4, xs4 + wid * 128 + v * 64);
        }
        if (lane < 32) {                         // 1 vmem instr/wave (masked)
            GLOAD_LDS16(W + (size_t)c * 512 + (wid * 32 + lane) * 4, ws4 + wid * 32);
        }
    };

    float4 acc[4];
#pragma unroll
    for (int g = 0; g < 4; ++g) acc[g] = make_float4(0.f, 0.f, 0.f, 0.f);

    stage(0);
    stage(1);
    asm volatile("s_waitcnt vmcnt(3)" ::: "memory");  // stage 0 resident
    __builtin_amdgcn_sched_barrier(0);
    __builtin_amdgcn_s_barrier();
    __builtin_amdgcn_sched_barrier(0);

    for (int c = 0; c < 24; ++c) {
        if (c + 2 < 24) stage(c + 2);
        const int b = c % 3;
        const float4* xs4 = smem + b * 512;
        const float4* ws4 = smem + 1536 + b * 128;
#pragma unroll
        for (int step = 0; step < 2; ++step) {
            int k = kq * 8 + step * 4;
            float4 w0 = ws4[(k + 0) * 4 + jq];
            float4 w1 = ws4[(k + 1) * 4 + jq];
            float4 w2 = ws4[(k + 2) * 4 + jq];
            float4 w3 = ws4[(k + 3) * 4 + jq];
            int k4 = k >> 2;
#pragma unroll
            for (int g = 0; g < 4; ++g) {
                int n = nq + (g << 4);
                float4 xv = xs4[n * 8 + (k4 ^ (n & 7))];
                fma4(acc[g], xv.x, w0);
                fma4(acc[g], xv.y, w1);
                fma4(acc[g], xv.z, w2);
                fma4(acc[g], xv.w, w3);
            }
        }
        if (c < 23) {
            if (c < 22) { asm volatile("s_waitcnt vmcnt(3)" ::: "memory"); }
            else        { asm volatile("s_waitcnt vmcnt(0)" ::: "memory"); }
            __builtin_amdgcn_sched_barrier(0);
            __builtin_amdgcn_s_barrier();
            __builtin_amdgcn_sched_barrier(0);
        }
    }
    __syncthreads();  // all compute done before smem reuse

    // cross-wave (kq) reduction via LDS: red[lane][g][kq], stride 17
    float4* red4 = smem;
#pragma unroll
    for (int g = 0; g < 4; ++g)
        red4[lane * 17 + g * 4 + kq] = acc[g];
    __syncthreads();

    // write-out: 256 threads = (lane_r 0..63, g_r 0..3)
    {
        int lane_r = tid & 63;
        int g_r = tid >> 6;
        float4 a0 = red4[lane_r * 17 + g_r * 4 + 0];
        float4 a1 = red4[lane_r * 17 + g_r * 4 + 1];
        float4 a2 = red4[lane_r * 17 + g_r * 4 + 2];
        float4 a3 = red4[lane_r * 17 + g_r * 4 + 3];
        int j4 = lane_r >> 4;
        float4 bb = *reinterpret_cast<const float4*>(B + j4 * 4);
        float4 r;
        r.x = leaky(a0.x + a1.x + a2.x + a3.x + bb.x);
        r.y = leaky(a0.y + a1.y + a2.y + a3.y + bb.y);
        r.z = leaky(a0.z + a1.z + a2.z + a3.z + bb.z);
        r.w = leaky(a0.w + a1.w + a2.w + a3.w + bb.w);
        int n = (lane_r & 15) + (g_r << 4);
        if (n0 + n < N)
            *reinterpret_cast<float4*>(x1g + (size_t)(n0 + n) * 64 + f * 16 + j4 * 4) = r;
    }
}

// ---------------------------------------------------------------------------
// Generic 64x64 node-matmul: out = act( xin @ W [+ bias] ) [* dinv]
// tobf16: write bf16 (for the z tensor consumed by the gather kernel).
__global__ __launch_bounds__(256, 4) void k_mm64(const float* __restrict__ xin,
                                                 const float* __restrict__ W,
                                                 const float* __restrict__ bias,
                                                 const float* __restrict__ dinvv,
                                                 int act, int tobf16,
                                                 void* __restrict__ outp, int N) {
    __shared__ float4 xt4[1024];  // [64][16] swizzled
    __shared__ float4 wt4[1024];  // [64 k][16 j4] linear
    const int tid = threadIdx.x;
    const int n0 = blockIdx.x * 64;
#pragma unroll
    for (int v = 0; v < 4; ++v) {
        int L = v * 256 + tid;
        int n = L >> 4, c4 = L & 15;
        int nn = n0 + n; if (nn >= N) nn = N - 1;
        xt4[n * 16 + (c4 ^ (n & 15))] = *reinterpret_cast<const float4*>(xin + (size_t)nn * 64 + c4 * 4);
        wt4[L] = *reinterpret_cast<const float4*>(W + (size_t)L * 4);
    }
    __syncthreads();
    const int nq = tid & 15;
    const int jq = tid >> 4;  // 0..15
    float4 acc[4];
#pragma unroll
    for (int g = 0; g < 4; ++g) acc[g] = make_float4(0.f, 0.f, 0.f, 0.f);
    for (int k = 0; k < 64; k += 4) {
        float4 w0 = wt4[(k + 0) * 16 + jq];
        float4 w1 = wt4[(k + 1) * 16 + jq];
        float4 w2 = wt4[(k + 2) * 16 + jq];
        float4 w3 = wt4[(k + 3) * 16 + jq];
        int k4 = k >> 2;
#pragma unroll
        for (int g = 0; g < 4; ++g) {
            int n = nq + (g << 4);
            float4 xv = xt4[n * 16 + (k4 ^ (n & 15))];
            fma4(acc[g], xv.x, w0);
            fma4(acc[g], xv.y, w1);
            fma4(acc[g], xv.z, w2);
            fma4(acc[g], xv.w, w3);
        }
    }
    float4 bb = make_float4(0.f, 0.f, 0.f, 0.f);
    if (bias) bb = *reinterpret_cast<const float4*>(bias + jq * 4);
#pragma unroll
    for (int g = 0; g < 4; ++g) {
        int n = nq + (g << 4);
        if (n0 + n >= N) continue;
        float4 r = acc[g];
        r.x += bb.x; r.y += bb.y; r.z += bb.z; r.w += bb.w;
        if (act) { r.x = leaky(r.x); r.y = leaky(r.y); r.z = leaky(r.z); r.w = leaky(r.w); }
        if (dinvv) {
            float dv = dinvv[n0 + n];
            r.x *= dv; r.y *= dv; r.z *= dv; r.w *= dv;
        }
        if (tobf16) {
            ushort4 o;
            o.x = f2bf(r.x); o.y = f2bf(r.y); o.z = f2bf(r.z); o.w = f2bf(r.w);
            *reinterpret_cast<ushort4*>((unsigned short*)outp + (size_t)(n0 + n) * 64 + jq * 4) = o;
        } else {
            *reinterpret_cast<float4*>((float*)outp + (size_t)(n0 + n) * 64 + jq * 4) = r;
        }
    }
}

// ---------------------------------------------------------------------------
// Gather aggregation: bf16 z, scalar CSR loads, 8-deep independent unroll.
__global__ __launch_bounds__(256) void k_agg(const unsigned short* __restrict__ z,
                                             const int* __restrict__ offs,
                                             const int* __restrict__ csr,
                                             const float* __restrict__ dinv,
                                             const float* __restrict__ bias,
                                             const float* __restrict__ x1,
                                             float* __restrict__ xout, int N) {
    int lane = threadIdx.x & 63;
    int c = blockIdx.x * 4 + (threadIdx.x >> 6);
    if (c >= N) return;
    int s = __builtin_amdgcn_readfirstlane(offs[c]);
    int e = __builtin_amdgcn_readfirstlane(offs[c + 1]);
    const unsigned short* zl = z + lane;
    float acc = bf2f(zl[(size_t)c * 64]);  // self-loop term
    float a0 = 0.f, a1 = 0.f, a2 = 0.f, a3 = 0.f;
    float a4 = 0.f, a5 = 0.f, a6 = 0.f, a7 = 0.f;
    int j = s;
    for (; j + 8 <= e; j += 8) {
        int r0 = csr[j + 0], r1 = csr[j + 1], r2 = csr[j + 2], r3 = csr[j + 3];
        int r4 = csr[j + 4], r5 = csr[j + 5], r6 = csr[j + 6], r7 = csr[j + 7];
        a0 += bf2f(zl[(size_t)r0 * 64]);
        a1 += bf2f(zl[(size_t)r1 * 64]);
        a2 += bf2f(zl[(size_t)r2 * 64]);
        a3 += bf2f(zl[(size_t)r3 * 64]);
        a4 += bf2f(zl[(size_t)r4 * 64]);
        a5 += bf2f(zl[(size_t)r5 * 64]);
        a6 += bf2f(zl[(size_t)r6 * 64]);
        a7 += bf2f(zl[(size_t)r7 * 64]);
    }
    for (; j < e; ++j) acc += bf2f(zl[(size_t)csr[j] * 64]);
    acc += ((a0 + a1) + (a2 + a3)) + ((a4 + a5) + (a6 + a7));
    xout[(size_t)c * 64 + lane] = dinv[c] * acc + bias[lane] + x1[(size_t)c * 64 + lane];
}

// ---------------------------------------------------------------------------
// head (unchanged)
__global__ __launch_bounds__(256) void k_head(const float* __restrict__ xin,
                                              const float* __restrict__ Wo1,
                                              const float* __restrict__ bo1,
                                              const float* __restrict__ Wo2,
                                              const float* __restrict__ bo2,
                                              float* __restrict__ out, int N) {
    __shared__ float xsg[64][65];
    __shared__ float wg[64][65];
    __shared__ float hs[64][65];
    __shared__ float wo2[128];
    const int tid = threadIdx.x;
    const int n0 = blockIdx.x * 64;
#pragma unroll
    for (int v = 0; v < 4; ++v) {
        int idx = tid + v * 256;
        int n = idx >> 4;
        int jj = (idx & 15) << 2;
        float4 xv = make_float4(0.f, 0.f, 0.f, 0.f);
        if (n0 + n < N) xv = *reinterpret_cast<const float4*>(xin + (size_t)(n0 + n) * 64 + jj);
        xsg[n][jj] = xv.x; xsg[n][jj + 1] = xv.y; xsg[n][jj + 2] = xv.z; xsg[n][jj + 3] = xv.w;
        float4 w = *reinterpret_cast<const float4*>(Wo1 + (size_t)n * 64 + jj);
        wg[n][jj] = w.x; wg[n][jj + 1] = w.y; wg[n][jj + 2] = w.z; wg[n][jj + 3] = w.w;
    }
    if (tid < 128) wo2[tid] = Wo2[tid];
    __syncthreads();
    int j = tid & 63;
    int g = tid >> 6;
    float bj = bo1[j];
    for (int i = 0; i < 16; ++i) {
        int n = g * 16 + i;
        float a = bj;
#pragma unroll
        for (int k = 0; k < 64; ++k) a += xsg[n][k] * wg[k][j];
        hs[n][j] = leaky(a);
    }
    __syncthreads();
    if (tid < 128) {
        int n = tid >> 1;
        int j2 = tid & 1;
        float a = bo2[j2];
#pragma unroll
        for (int k = 0; k < 64; ++k) a += hs[n][k] * wo2[k * 2 + j2];
        if (n0 + n < N) out[(size_t)(n0 + n) * 2 + j2] = 1.f / (1.f + expf(-a));
    }
}

// ---------------------------------------------------------------------------
extern "C" void kernel_launch(void* const* d_in, const int* in_sizes, int n_in,
                              void* d_out, int out_size, void* d_ws, size_t ws_size,
                              hipStream_t stream) {
    const float* screen   = (const float*)d_in[0];
    const float* des      = (const float*)d_in[1];
    const float* tweet    = (const float*)d_in[2];
    const float* profile  = (const float*)d_in[3];
    const float* personal = (const float*)d_in[4];
    const int*   edge     = (const int*)d_in[5];
    const float* Ws  = (const float*)d_in[6],  *bs  = (const float*)d_in[7];
    const float* Wd  = (const float*)d_in[8],  *bd  = (const float*)d_in[9];
    const float* Wt  = (const float*)d_in[10], *bt  = (const float*)d_in[11];
    const float* Wp  = (const float*)d_in[12], *bp  = (const float*)d_in[13];
    const float* Wpe = (const float*)d_in[14], *bpe = (const float*)d_in[15];
    const float* Wl  = (const float*)d_in[16], *bl  = (const float*)d_in[17];
    const float* Wg1 = (const float*)d_in[18], *bg1 = (const float*)d_in[19];
    const float* Wg2 = (const float*)d_in[20], *bg2 = (const float*)d_in[21];
    const float* Wg3 = (const float*)d_in[22], *bg3 = (const float*)d_in[23];
    const float* Wo1 = (const float*)d_in[24], *bo1 = (const float*)d_in[25];
    const float* Wo2 = (const float*)d_in[26], *bo2 = (const float*)d_in[27];

    const int N = in_sizes[0] / 768;   // 50000
    const int E = in_sizes[5] / 2;     // 1600000
    const int* row = edge;
    const int* col = edge + E;

    size_t off = 0;
    auto alloc = [&](size_t bytes) -> void* {
        void* p = (char*)d_ws + off;
        off += (bytes + 255) & ~(size_t)255;
        return p;
    };
    const size_t NF = (size_t)N * 64;
    float* x1   = (float*)alloc(NF * 4);
    float* xa   = (float*)alloc(NF * 4);
    float* xb   = (float*)alloc(NF * 4);
    unsigned short* z = (unsigned short*)alloc(NF * 2);
    float* dinv = (float*)alloc((size_t)N * 4);
    int* deg  = (int*)alloc((size_t)N * 4);
    int* part = (int*)alloc((size_t)N * 4);
    int* offs = (int*)alloc((size_t)(N + 1) * 4);
    int* pos  = (int*)alloc((size_t)N * 4);
    int* csr  = (int*)alloc((size_t)E * 4);
    const int NB = (N + 255) / 256;
    int* bsum = (int*)alloc((size_t)NB * 4);
    int* boff = (int*)alloc((size_t)NB * 4);
    (void)ws_size; (void)n_in; (void)out_size;

    // CSR build
    hipMemsetAsync(deg, 0, (size_t)N * 4, stream);
    k_deg<<<(E + 255) / 256, 256, 0, stream>>>(col, E, deg);
    k_scan_part<<<NB, 256, 0, stream>>>(deg, part, bsum, N);
    k_scan_sums<<<1, 256, 0, stream>>>(bsum, boff, NB, offs + N);
    k_scan_final<<<NB, 256, 0, stream>>>(part, boff, deg, offs, pos, dinv, N);
    k_fill<<<(E + 255) / 256, 256, 0, stream>>>(row, col, E, pos, csr);

    // Phase A: feature linears (64-node tiles) + fused tiny linears
    const int NG = (N + 63) / 64;
    const int NSM = (N + 255) / 256;
    k_featB<<<NG * 3 + NSM, 256, 0, stream>>>(screen, des, tweet,
                                              Ws, bs, Wd, bd, Wt, bt,
                                              profile, personal, Wp, bp, Wpe, bpe,
                                              x1, N, NG);

    const int NGB = (N + 63) / 64;
    // x = leaky(x1 @ Wl + bl)
    k_mm64<<<NGB, 256, 0, stream>>>(x1, Wl, bl, nullptr, 1, 0, xa, N);

    const int NAB = (N + 3) / 4;
    // layer 1
    k_mm64<<<NGB, 256, 0, stream>>>(xa, Wg1, nullptr, dinv, 0, 1, z, N);
    k_agg<<<NAB, 256, 0, stream>>>(z, offs, csr, dinv, bg1, x1, xb, N);
    // layer 2
    k_mm64<<<NGB, 256, 0, stream>>>(xb, Wg2, nullptr, dinv, 0, 1, z, N);
    k_agg<<<NAB, 256, 0, stream>>>(z, offs, csr, dinv, bg2, x1, xa, N);
    // layer 3
    k_mm64<<<NGB, 256, 0, stream>>>(xa, Wg3, nullptr, dinv, 0, 1, z, N);
    k_agg<<<NAB, 256, 0, stream>>>(z, offs, csr, dinv, bg3, x1, xb, N);

    // head
    k_head<<<NGB, 256, 0, stream>>>(xb, Wo1, bo1, Wo2, bo2, (float*)d_out, N);
}